// Round 16
// baseline (225.412 us; speedup 1.0000x reference)
//
#include <hip/hip_runtime.h>
#include <hip/hip_bf16.h>
#include <cstdint>
#include <type_traits>

using bf16_t = __hip_bfloat16;
typedef __bf16 bf16x8 __attribute__((ext_vector_type(8)));
typedef float f32x4 __attribute__((ext_vector_type(4)));

typedef __attribute__((address_space(3))) uint32_t lds_u32_t;
typedef const __attribute__((address_space(1))) uint32_t glb_u32_t;

// ---------------- fused f32 -> bf16 convert (x, W_attn, W_proj) ----------
__global__ void cvt3(const float* __restrict__ x, const float* __restrict__ wa,
                     const float* __restrict__ wp, bf16_t* __restrict__ xb,
                     bf16_t* __restrict__ wab, bf16_t* __restrict__ wpb) {
  int i = blockIdx.x * blockDim.x + threadIdx.x;  // group of 8 elems
  const float* src;
  bf16_t* dst;
  int off;
  if (i < 1048576) {
    src = x; dst = xb; off = i;
  } else if (i < 1835008) {
    src = wa; dst = wab; off = i - 1048576;
  } else {
    src = wp; dst = wpb; off = i - 1835008;
  }
  const float4* p = reinterpret_cast<const float4*>(src) + (size_t)off * 2;
  float4 a = p[0];
  float4 b = p[1];
  bf16_t o[8];
  o[0] = __float2bfloat16(a.x); o[1] = __float2bfloat16(a.y);
  o[2] = __float2bfloat16(a.z); o[3] = __float2bfloat16(a.w);
  o[4] = __float2bfloat16(b.x); o[5] = __float2bfloat16(b.y);
  o[6] = __float2bfloat16(b.z); o[7] = __float2bfloat16(b.w);
  *reinterpret_cast<uint4*>(dst + (size_t)off * 8) = *reinterpret_cast<const uint4*>(o);
}

// ---------------- bf16 GEMM, 256xBN tile, counted-vmcnt + interleave -----
// C[M,N] = A[M,K] * Bt[N,K]^T.  512 thr = 8 waves (2M x 4N), per-wave
// 128 x BN/4 output, BK=64, LDS dbuf, grid = 256 blocks = 1/CU.
// r13 skeleton (2 barriers, 1-tile-lag counted waits, never vmcnt(0) in
// steady state) with regions SWAPPED so the big A-read stream is fused
// with the MFMA cluster:
//   region1 [vmcnt(4): B(t) landed]: read 2*JN bb frags; stageB(t+1)
//   region2 [vmcnt(BL): A(t) landed; B(t+1) in flight]: stageA(t+1);
//            i-loop { read a[i] (2x b128) ; 2*JN MFMA } -- each a[i]'s
//            lgkm wait hides under a[i-1]'s MFMAs (m97 compiler behavior).
// Removes the 384cyc/SIMD pure-LDS region that capped MfmaUtil at ~45%.
// T2 swizzle (pre-swizzled source + swizzled ds_read), T1 XCD swizzle.
template <int BN, typename OutT>
__global__ __launch_bounds__(512, 2) void gemm256(const bf16_t* __restrict__ A,
                                                  const bf16_t* __restrict__ Bt,
                                                  OutT* __restrict__ C,
                                                  int M, int N, int K) {
  constexpr int JN = BN / 64;
  constexpr int BL = BN / 64;
  __shared__ __align__(16) bf16_t As[2 * 256 * 64];
  __shared__ __align__(16) bf16_t Bs[2 * BN * 64];
  const int tid = threadIdx.x;
  const int lane = tid & 63;
  const int w = tid >> 6;
  const int wm = w >> 2, wn = w & 3;
  const int lr = lane & 15, lc = lane >> 4;

  const int nwg = gridDim.x * gridDim.y;
  const int orig = blockIdx.y * gridDim.x + blockIdx.x;
  const int cpx = nwg >> 3;
  const int swz = (orig & 7) * cpx + (orig >> 3);
  const int bx = swz % gridDim.x, by = swz / gridDim.x;
  const int m0 = by * 256, n0 = bx * BN;

  const int srow = tid >> 3;
  const int scol = ((tid & 7) ^ (srow & 7)) * 8;
  const bf16_t* Asrc = A + (size_t)(m0 + srow) * K + scol;
  const bf16_t* Bsrc = Bt + (size_t)(n0 + srow) * K + scol;

  f32x4 acc[8][JN] = {};

  auto stageA = [&](int bufi, int kt) {
#pragma unroll
    for (int l = 0; l < 4; ++l)
      __builtin_amdgcn_global_load_lds(
          (glb_u32_t*)(Asrc + (size_t)kt * 64 + (size_t)l * 64 * K),
          (lds_u32_t*)(As + bufi * 16384 + l * 4096 + w * 512), 16, 0, 0);
  };
  auto stageB = [&](int bufi, int kt) {
#pragma unroll
    for (int l = 0; l < BL; ++l)
      __builtin_amdgcn_global_load_lds(
          (glb_u32_t*)(Bsrc + (size_t)kt * 64 + (size_t)l * 64 * K),
          (lds_u32_t*)(Bs + bufi * BN * 64 + l * 4096 + w * 512), 16, 0, 0);
  };

  const int nt = K >> 6;
  // prologue: B FIRST, then A (FIFO order is what the counted waits assume)
  stageB(0, 0);
  stageA(0, 0);

  bf16x8 bb[JN][2];
  for (int t = 0; t < nt; ++t) {
    const int buf = t & 1;
    const char* Ab = (const char*)(As + buf * 16384);
    const char* Bb = (const char*)(Bs + buf * BN * 64);
    const bool st = (t + 1 < nt);

    auto rdA = [&](int i, int kk) {
      int R = wm * 128 + i * 16 + lr;
      return *reinterpret_cast<const bf16x8*>(
          Ab + R * 128 + ((kk * 64 + lc * 16) ^ ((R & 7) << 4)));
    };
    auto rdB = [&](int j, int kk) {
      int R = wn * (BN / 4) + j * 16 + lr;
      return *reinterpret_cast<const bf16x8*>(
          Bb + R * 128 + ((kk * 64 + lc * 16) ^ ((R & 7) << 4)));
    };

    // ---- region1: B(t) landed (leaves A(t)=4 outstanding) ----
    asm volatile("s_waitcnt vmcnt(4)" ::: "memory");
    __builtin_amdgcn_s_barrier();
#pragma unroll
    for (int j = 0; j < JN; ++j) { bb[j][0] = rdB(j, 0); bb[j][1] = rdB(j, 1); }
    if (st) stageB(buf ^ 1, t + 1);

    // ---- region2: A(t) landed; B(t+1) stays in flight ----
    if (st) {
      if constexpr (BL == 3) {
        asm volatile("s_waitcnt vmcnt(3)" ::: "memory");
      } else {
        asm volatile("s_waitcnt vmcnt(2)" ::: "memory");
      }
    } else {
      asm volatile("s_waitcnt vmcnt(0)" ::: "memory");
    }
    __builtin_amdgcn_s_barrier();
    if (st) stageA(buf ^ 1, t + 1);

    __builtin_amdgcn_s_setprio(1);
#pragma unroll
    for (int i = 0; i < 8; ++i) {
      bf16x8 a0 = rdA(i, 0);
      bf16x8 a1 = rdA(i, 1);
#pragma unroll
      for (int j = 0; j < JN; ++j) {
        acc[i][j] = __builtin_amdgcn_mfma_f32_16x16x32_bf16(a0, bb[j][0], acc[i][j], 0, 0, 0);
        acc[i][j] = __builtin_amdgcn_mfma_f32_16x16x32_bf16(a1, bb[j][1], acc[i][j], 0, 0, 0);
      }
    }
    __builtin_amdgcn_s_setprio(0);
  }

  // epilogue: C/D layout col=lane&15, row=(lane>>4)*4+reg  [m89/m91]
#pragma unroll
  for (int i = 0; i < 8; ++i)
#pragma unroll
    for (int j = 0; j < JN; ++j) {
      int row = m0 + wm * 128 + i * 16 + lc * 4;
      int col = n0 + wn * (BN / 4) + j * 16 + lr;
#pragma unroll
      for (int r = 0; r < 4; ++r) {
        float v = acc[i][j][r];
        if constexpr (std::is_same<OutT, float>::value)
          C[(size_t)(row + r) * N + col] = v;
        else
          C[(size_t)(row + r) * N + col] = __float2bfloat16(v);
      }
    }
}

// ---------------- RoPE (vectorized pair-units) -> Q (scaled), K ----------
__global__ __launch_bounds__(320) void rope_qk(const bf16_t* __restrict__ qkv,
                                               const float* __restrict__ cosp,
                                               const float* __restrict__ sinp,
                                               bf16_t* __restrict__ Q,
                                               bf16_t* __restrict__ K) {
  const int row = blockIdx.x * 2 + (threadIdx.x >= 160 ? 1 : 0);
  const int u = threadIdx.x >= 160 ? threadIdx.x - 160 : threadIdx.x;  // 0..159
  const int b = row >> 11, t = row & 2047;
  const int g = u / 40;
  const int r = u - g * 40;
  const int slot = r >> 3;       // 0..4
  const int d0 = (r & 7) * 8;    // 0..56 (lower half)

  const bf16_t* src = qkv + (size_t)row * 3072 + g * 768 + slot * 128 + d0;
  short lo[8], hi[8];
  *reinterpret_cast<uint4*>(lo) = *reinterpret_cast<const uint4*>(src);
  *reinterpret_cast<uint4*>(hi) = *reinterpret_cast<const uint4*>(src + 64);
  float4 c0 = *reinterpret_cast<const float4*>(cosp + t * 128 + d0);
  float4 c1 = *reinterpret_cast<const float4*>(cosp + t * 128 + d0 + 4);
  float4 s0 = *reinterpret_cast<const float4*>(sinp + t * 128 + d0);
  float4 s1 = *reinterpret_cast<const float4*>(sinp + t * 128 + d0 + 4);
  float cs[8] = {c0.x, c0.y, c0.z, c0.w, c1.x, c1.y, c1.z, c1.w};
  float sn[8] = {s0.x, s0.y, s0.z, s0.w, s1.x, s1.y, s1.z, s1.w};

  const bool isq = (slot < 4);
  const float scale = isq ? (0.08838834764831843f * 1.4426950408889634f) : 1.0f;

  bf16_t olo[8], ohi[8];
#pragma unroll
  for (int e = 0; e < 8; ++e) {
    float x1 = __bfloat162float(*reinterpret_cast<const bf16_t*>(&lo[e]));
    float x2 = __bfloat162float(*reinterpret_cast<const bf16_t*>(&hi[e]));
    olo[e] = __float2bfloat16((x1 * cs[e] - x2 * sn[e]) * scale);
    ohi[e] = __float2bfloat16((x2 * cs[e] + x1 * sn[e]) * scale);
  }

  bf16_t* dst;
  if (isq) {
    int h = g * 4 + slot;
    dst = Q + (((size_t)(b * 16 + h)) * 2048 + t) * 128 + d0;
  } else {
    dst = K + (((size_t)(b * 4 + g)) * 2048 + t) * 128 + d0;
  }
  *reinterpret_cast<uint4*>(dst) = *reinterpret_cast<const uint4*>(olo);
  *reinterpret_cast<uint4*>(dst + 64) = *reinterpret_cast<const uint4*>(ohi);
}

// ---------------- V slice of qkv [b*t][g*768+640+d] -> Vt [bg][d][t] -----
__global__ void transpose_v2(const bf16_t* __restrict__ qkv, bf16_t* __restrict__ Vt) {
  __shared__ bf16_t tile[32][33];
  const int bg = blockIdx.z;
  const int b = bg >> 2, g = bg & 3;
  const int t0 = blockIdx.x * 32;
  const int d0 = blockIdx.y * 32;
  const bf16_t* src = qkv + (size_t)b * 2048 * 3072 + g * 768 + 640;
  bf16_t* dst = Vt + (size_t)bg * 128 * 2048;
#pragma unroll
  for (int i = threadIdx.y; i < 32; i += 8)
    tile[i][threadIdx.x] = src[(size_t)(t0 + i) * 3072 + d0 + threadIdx.x];
  __syncthreads();
#pragma unroll
  for (int i = threadIdx.y; i < 32; i += 8)
    dst[(size_t)(d0 + i) * 2048 + t0 + threadIdx.x] = tile[threadIdx.x][i];
}

// ---------------- sliding-window flash attention (v10, plateau) ----------
#define VROW 40
__global__ __launch_bounds__(256) void attn_swa(const bf16_t* __restrict__ Q,
                                                const bf16_t* __restrict__ K,
                                                const bf16_t* __restrict__ Vt,
                                                bf16_t* __restrict__ Y) {
  __shared__ __align__(16) bf16_t Ks[2 * 32 * 128];
  __shared__ __align__(16) bf16_t Vs[2 * 128 * VROW];

  const int tid = threadIdx.x;
  const int lane = tid & 63;
  const int w = tid >> 6;
  const int lr = lane & 15, lc = lane >> 4;
  const int b = blockIdx.z, h = blockIdx.y;
  const int g = h >> 2;

  int nseg, sx0, sx1 = 0;
  if (blockIdx.x < 16) {
    nseg = 1;
    sx0 = blockIdx.x + 16;
  } else {
    nseg = 2;
    sx0 = blockIdx.x - 16;
    sx1 = 15 - sx0;
  }

  const bf16_t* Qp = Q + ((size_t)(b * 16 + h) * 2048) * 128;
  const bf16_t* Kp = K + ((size_t)(b * 4 + g) * 2048) * 128;
  const bf16_t* Vp = Vt + ((size_t)(b * 4 + g) * 128) * 2048;

  const int kmj = tid >> 4;
  const int kmc = ((tid & 15) ^ (kmj & 7)) * 8;
  const bf16_t* Ksrc = Kp + (size_t)kmj * 128 + kmc;
  const int vd = tid >> 2, vc = tid & 3;
  const bf16_t* Vsrc = Vp + (size_t)vd * 2048 + vc * 8;
  const int vdst = vd * VROW + (vc & 1) * 16 + (vc >> 1) * 4;

  auto loadK = [&](int j0, uint4& ka, uint4& kb) {
    const bf16_t* s = Ksrc + (size_t)j0 * 128;
    ka = *reinterpret_cast<const uint4*>(s);
    kb = *reinterpret_cast<const uint4*>(s + 16 * 128);
  };
  auto writeK = [&](int bufi, uint4 ka, uint4 kb) {
    *reinterpret_cast<uint4*>(Ks + bufi * 4096 + tid * 8) = ka;
    *reinterpret_cast<uint4*>(Ks + bufi * 4096 + 2048 + tid * 8) = kb;
  };
  auto loadV = [&](int j0, uint4& a, uint4& bqv) {
    a = *reinterpret_cast<const uint4*>(Vsrc + j0);
    bqv = *reinterpret_cast<const uint4*>(Vsrc + 64 * 2048 + j0);
  };
  auto writeV = [&](int bufi, uint4 a, uint4 bqv) {
    bf16_t* p = Vs + bufi * 128 * VROW + vdst;
    *reinterpret_cast<uint2*>(p) = make_uint2(a.x, a.y);
    *reinterpret_cast<uint2*>(p + 8) = make_uint2(a.z, a.w);
    bf16_t* p1 = p + 64 * VROW;
    *reinterpret_cast<uint2*>(p1) = make_uint2(bqv.x, bqv.y);
    *reinterpret_cast<uint2*>(p1 + 8) = make_uint2(bqv.z, bqv.w);
  };

  const int kxor = (lr & 7) << 4;

  for (int sidx = 0; sidx < nseg; ++sidx) {
    const int i0b = ((sidx == 0) ? sx0 : sx1) * 64;
    const int i0 = i0b + w * 16;
    const int qrow = i0 + lr;

    bf16x8 qf[4];
#pragma unroll
    for (int kc = 0; kc < 4; ++kc)
      qf[kc] = *reinterpret_cast<const bf16x8*>(&Qp[(size_t)qrow * 128 + kc * 32 + lc * 8]);

    f32x4 o[8] = {};
    float mrun = -1e30f, lrun = 0.f;  // lrun LANE-PARTIAL (reduced at epilogue)

    int lo = i0b - 1023;
    if (lo < 0) lo = 0;
    const int jstart = lo & ~31;
    const int jlast = i0b + 32;

    {
      uint4 ka, kb, va, vb;
      loadK(jstart, ka, kb);
      loadV(jstart, va, vb);
      writeK(0, ka, kb);
      writeV(0, va, vb);
    }
    __syncthreads();

    int buf = 0;
    for (int j0 = jstart; j0 <= jlast; j0 += 32) {
      const int nxt = j0 + 32;
      uint4 ka, kb, va, vb;
      const bool do_stage = (nxt <= jlast);
      if (do_stage) {
        loadK(nxt, ka, kb);
        loadV(nxt, va, vb);
      }

      const bool active = (j0 <= i0 + 15) && (j0 + 31 > i0 - 1024);
      if (active) {
        const bf16_t* Kb = Ks + buf * 4096;
        const bf16_t* Vb = Vs + buf * 128 * VROW;
        f32x4 s0 = {}, s1 = {};
        __builtin_amdgcn_s_setprio(1);
#pragma unroll
        for (int kc = 0; kc < 4; ++kc) {
          int col = ((kc * 64 + lc * 16) ^ kxor) >> 1;
          bf16x8 kf0 = *reinterpret_cast<const bf16x8*>(Kb + lr * 128 + col);
          bf16x8 kf1 = *reinterpret_cast<const bf16x8*>(Kb + (16 + lr) * 128 + col);
          s0 = __builtin_amdgcn_mfma_f32_16x16x32_bf16(kf0, qf[kc], s0, 0, 0, 0);
          s1 = __builtin_amdgcn_mfma_f32_16x16x32_bf16(kf1, qf[kc], s1, 0, 0, 0);
        }
        __builtin_amdgcn_s_setprio(0);
        bf16x8 vvf[8];
#pragma unroll
        for (int f = 0; f < 8; ++f)
          vvf[f] = *reinterpret_cast<const bf16x8*>(Vb + (f * 16 + lr) * VROW + lc * 8);

        const bool full = (j0 + 31 <= i0) && (j0 >= i0 - 1008);
        if (!full) {
#pragma unroll
          for (int r = 0; r < 4; ++r) {
            int ja = j0 + lc * 4 + r;
            int jb = ja + 16;
            bool oka = (ja <= qrow) && (ja > qrow - 1024);
            bool okb = (jb <= qrow) && (jb > qrow - 1024);
            s0[r] = oka ? s0[r] : -1e30f;
            s1[r] = okb ? s1[r] : -1e30f;
          }
        }
        float rm = fmaxf(fmaxf(fmaxf(s0[0], s0[1]), fmaxf(s0[2], s0[3])),
                         fmaxf(fmaxf(s1[0], s1[1]), fmaxf(s1[2], s1[3])));

        if (!__all(rm <= mrun + 11.5f)) {
          rm = fmaxf(rm, __shfl_xor(rm, 16));
          rm = fmaxf(rm, __shfl_xor(rm, 32));
          float mnew = fmaxf(mrun, rm);
          float alpha = exp2f(mrun - mnew);
          mrun = mnew;
          lrun *= alpha;
#pragma unroll
          for (int f = 0; f < 8; ++f)
#pragma unroll
            for (int r = 0; r < 4; ++r) o[f][r] *= alpha;
        }

        float p0[4], p1[4], ps = 0.f;
#pragma unroll
        for (int r = 0; r < 4; ++r) {
          p0[r] = exp2f(s0[r] - mrun);
          p1[r] = exp2f(s1[r] - mrun);
          ps += p0[r] + p1[r];
        }
        lrun += ps;

        bf16_t pb[8];
#pragma unroll
        for (int r = 0; r < 4; ++r) {
          pb[r] = __float2bfloat16(p0[r]);
          pb[r + 4] = __float2bfloat16(p1[r]);
        }
        bf16x8 pfrag = *reinterpret_cast<bf16x8*>(pb);

        __builtin_amdgcn_s_setprio(1);
#pragma unroll
        for (int f = 0; f < 8; ++f)
          o[f] = __builtin_amdgcn_mfma_f32_16x16x32_bf16(vvf[f], pfrag, o[f], 0, 0, 0);
        __builtin_amdgcn_s_setprio(0);
      }

      if (do_stage) {
        writeK(buf ^ 1, ka, kb);
        writeV(buf ^ 1, va, vb);
      }
      __syncthreads();
      buf ^= 1;
    }

    float lt = lrun;
    lt += __shfl_xor(lt, 16);
    lt += __shfl_xor(lt, 32);
    float inv = 1.f / lt;
#pragma unroll
    for (int f = 0; f < 8; ++f) {
      bf16_t ob[4];
#pragma unroll
      for (int r = 0; r < 4; ++r) ob[r] = __float2bfloat16(o[f][r] * inv);
      *reinterpret_cast<uint2*>(
          &Y[((size_t)(b * 2048 + qrow)) * 2048 + h * 128 + f * 16 + lc * 4]) =
          *reinterpret_cast<uint2*>(ob);
    }
  }
}

// ---------------- launch ----------------
extern "C" void kernel_launch(void* const* d_in, const int* in_sizes, int n_in,
                              void* d_out, int out_size, void* d_ws, size_t ws_size,
                              hipStream_t stream) {
  const float* x = (const float*)d_in[0];
  const float* cosp = (const float*)d_in[1];
  const float* sinp = (const float*)d_in[2];
  const float* Wa = (const float*)d_in[3];
  const float* Wp = (const float*)d_in[4];
  float* out = (float*)d_out;

  bf16_t* ws = (bf16_t*)d_ws;
  bf16_t* xb = ws;                  // x bf16 -> reused as Q
  bf16_t* wab = ws + 8388608;       // W_attn bf16 -> reused as K
  bf16_t* wpb = ws + 14680064;      // W_proj bf16
  bf16_t* qkv = ws + 18874368;      // qkv bf16 -> reused as Y,Vt
  bf16_t* Q = xb;                   // [B][H][T][HS]
  bf16_t* Kr = wab;                 // [B][G][T][HS]
  bf16_t* Y = qkv;                  // [B][T][H][HS]
  bf16_t* Vt = qkv + 8388608;       // [B][G][HS][T]

  // fused converts: 2359296 groups of 8 = x(1048576) + Wa(786432) + Wp(524288)
  cvt3<<<9216, 256, 0, stream>>>(x, Wa, Wp, xb, wab, wpb);

  // qkv = xb @ wab^T : M=4096 N=3072 K=2048  (BN=192 -> 256 blocks)
  gemm256<192, bf16_t><<<dim3(16, 16), 512, 0, stream>>>(xb, wab, qkv, 4096, 3072, 2048);

  // RoPE Q/K only (V slice consumed by transpose_v2 straight from qkv)
  rope_qk<<<2048, 320, 0, stream>>>(qkv, cosp, sinp, Q, Kr);

  transpose_v2<<<dim3(64, 4, 8), dim3(32, 8), 0, stream>>>(qkv, Vt);

  attn_swa<<<dim3(24, 16, 2), 256, 0, stream>>>(Q, Kr, Vt, Y);

  // out = Y @ wpb^T : M=4096 N=2048 K=2048  (BN=128 -> 256 blocks)
  gemm256<128, float><<<dim3(16, 16), 512, 0, stream>>>(Y, wpb, out, 4096, 2048, 2048);
}

// Round 17
// 219.563 us; speedup vs baseline: 1.0266x; 1.0266x over previous
//
#include <hip/hip_runtime.h>
#include <hip/hip_bf16.h>
#include <cstdint>
#include <type_traits>

using bf16_t = __hip_bfloat16;
typedef __bf16 bf16x8 __attribute__((ext_vector_type(8)));
typedef float f32x4 __attribute__((ext_vector_type(4)));

typedef __attribute__((address_space(3))) uint32_t lds_u32_t;
typedef const __attribute__((address_space(1))) uint32_t glb_u32_t;

// ---------------- fused f32 -> bf16 convert (x, W_attn, W_proj) ----------
__global__ void cvt3(const float* __restrict__ x, const float* __restrict__ wa,
                     const float* __restrict__ wp, bf16_t* __restrict__ xb,
                     bf16_t* __restrict__ wab, bf16_t* __restrict__ wpb) {
  int i = blockIdx.x * blockDim.x + threadIdx.x;  // group of 8 elems
  const float* src;
  bf16_t* dst;
  int off;
  if (i < 1048576) {
    src = x; dst = xb; off = i;
  } else if (i < 1835008) {
    src = wa; dst = wab; off = i - 1048576;
  } else {
    src = wp; dst = wpb; off = i - 1835008;
  }
  const float4* p = reinterpret_cast<const float4*>(src) + (size_t)off * 2;
  float4 a = p[0];
  float4 b = p[1];
  bf16_t o[8];
  o[0] = __float2bfloat16(a.x); o[1] = __float2bfloat16(a.y);
  o[2] = __float2bfloat16(a.z); o[3] = __float2bfloat16(a.w);
  o[4] = __float2bfloat16(b.x); o[5] = __float2bfloat16(b.y);
  o[6] = __float2bfloat16(b.z); o[7] = __float2bfloat16(b.w);
  *reinterpret_cast<uint4*>(dst + (size_t)off * 8) = *reinterpret_cast<const uint4*>(o);
}

// ---------------- bf16 GEMM, 256xBN tile, 1-barrier counted pipeline -----
// C[M,N] = A[M,K] * Bt[N,K]^T.  512 thr = 8 waves (2M x 4N), per-wave
// 128 x BN/4 output, BK=64, LDS dbuf, grid = 256 blocks = 1/CU.
// Per tile: vmcnt(0) [drains only tile-t DMA, issued a full tile ago ->
// free] -> barrier [publishes: all waves' DMA landed AND all waves' t-1
// reads retired] -> issue stage(t+1) into buf^1 [safe by the barrier] ->
// read all frags -> setprio MFMA cluster. One barrier/tile (r13 had two);
// t+1's DMA spans the whole read+MFMA region.
// T2 swizzle (pre-swizzled source + swizzled ds_read), T1 XCD swizzle.
template <int BN, typename OutT>
__global__ __launch_bounds__(512, 2) void gemm256(const bf16_t* __restrict__ A,
                                                  const bf16_t* __restrict__ Bt,
                                                  OutT* __restrict__ C,
                                                  int M, int N, int K) {
  constexpr int JN = BN / 64;
  constexpr int BL = BN / 64;
  __shared__ __align__(16) bf16_t As[2 * 256 * 64];
  __shared__ __align__(16) bf16_t Bs[2 * BN * 64];
  const int tid = threadIdx.x;
  const int lane = tid & 63;
  const int w = tid >> 6;
  const int wm = w >> 2, wn = w & 3;
  const int lr = lane & 15, lc = lane >> 4;

  const int nwg = gridDim.x * gridDim.y;
  const int orig = blockIdx.y * gridDim.x + blockIdx.x;
  const int cpx = nwg >> 3;
  const int swz = (orig & 7) * cpx + (orig >> 3);
  const int bx = swz % gridDim.x, by = swz / gridDim.x;
  const int m0 = by * 256, n0 = bx * BN;

  const int srow = tid >> 3;
  const int scol = ((tid & 7) ^ (srow & 7)) * 8;
  const bf16_t* Asrc = A + (size_t)(m0 + srow) * K + scol;
  const bf16_t* Bsrc = Bt + (size_t)(n0 + srow) * K + scol;

  f32x4 acc[8][JN] = {};

  auto stageA = [&](int bufi, int kt) {
#pragma unroll
    for (int l = 0; l < 4; ++l)
      __builtin_amdgcn_global_load_lds(
          (glb_u32_t*)(Asrc + (size_t)kt * 64 + (size_t)l * 64 * K),
          (lds_u32_t*)(As + bufi * 16384 + l * 4096 + w * 512), 16, 0, 0);
  };
  auto stageB = [&](int bufi, int kt) {
#pragma unroll
    for (int l = 0; l < BL; ++l)
      __builtin_amdgcn_global_load_lds(
          (glb_u32_t*)(Bsrc + (size_t)kt * 64 + (size_t)l * 64 * K),
          (lds_u32_t*)(Bs + bufi * BN * 64 + l * 4096 + w * 512), 16, 0, 0);
  };

  const int nt = K >> 6;
  // prologue: stage tile 0 into buf 0
  stageA(0, 0);
  stageB(0, 0);

  bf16x8 a[8][2], bb[JN][2];
  for (int t = 0; t < nt; ++t) {
    const int buf = t & 1;
    const char* Ab = (const char*)(As + buf * 16384);
    const char* Bb = (const char*)(Bs + buf * BN * 64);
    const bool st = (t + 1 < nt);

    auto rdA = [&](int i, int kk) {
      int R = wm * 128 + i * 16 + lr;
      return *reinterpret_cast<const bf16x8*>(
          Ab + R * 128 + ((kk * 64 + lc * 16) ^ ((R & 7) << 4)));
    };
    auto rdB = [&](int j, int kk) {
      int R = wn * (BN / 4) + j * 16 + lr;
      return *reinterpret_cast<const bf16x8*>(
          Bb + R * 128 + ((kk * 64 + lc * 16) ^ ((R & 7) << 4)));
    };

    // own tile-t DMA landed (issued a full tile ago -> free in steady state)
    asm volatile("s_waitcnt vmcnt(0)" ::: "memory");
    // all waves: DMA landed + t-1 reads retired -> buf readable, buf^1 free
    __builtin_amdgcn_s_barrier();
    if (st) {
      stageA(buf ^ 1, t + 1);  // spans the entire read+MFMA region below
      stageB(buf ^ 1, t + 1);
    }

#pragma unroll
    for (int i = 0; i < 8; ++i) { a[i][0] = rdA(i, 0); a[i][1] = rdA(i, 1); }
#pragma unroll
    for (int j = 0; j < JN; ++j) { bb[j][0] = rdB(j, 0); bb[j][1] = rdB(j, 1); }

    __builtin_amdgcn_s_setprio(1);
#pragma unroll
    for (int i = 0; i < 8; ++i)
#pragma unroll
      for (int j = 0; j < JN; ++j) {
        acc[i][j] = __builtin_amdgcn_mfma_f32_16x16x32_bf16(a[i][0], bb[j][0], acc[i][j], 0, 0, 0);
        acc[i][j] = __builtin_amdgcn_mfma_f32_16x16x32_bf16(a[i][1], bb[j][1], acc[i][j], 0, 0, 0);
      }
    __builtin_amdgcn_s_setprio(0);
  }

  // epilogue: C/D layout col=lane&15, row=(lane>>4)*4+reg  [m89/m91]
#pragma unroll
  for (int i = 0; i < 8; ++i)
#pragma unroll
    for (int j = 0; j < JN; ++j) {
      int row = m0 + wm * 128 + i * 16 + lc * 4;
      int col = n0 + wn * (BN / 4) + j * 16 + lr;
#pragma unroll
      for (int r = 0; r < 4; ++r) {
        float v = acc[i][j][r];
        if constexpr (std::is_same<OutT, float>::value)
          C[(size_t)(row + r) * N + col] = v;
        else
          C[(size_t)(row + r) * N + col] = __float2bfloat16(v);
      }
    }
}

// ---------------- RoPE (vectorized pair-units) -> Q (scaled), K ----------
__global__ __launch_bounds__(320) void rope_qk(const bf16_t* __restrict__ qkv,
                                               const float* __restrict__ cosp,
                                               const float* __restrict__ sinp,
                                               bf16_t* __restrict__ Q,
                                               bf16_t* __restrict__ K) {
  const int row = blockIdx.x * 2 + (threadIdx.x >= 160 ? 1 : 0);
  const int u = threadIdx.x >= 160 ? threadIdx.x - 160 : threadIdx.x;  // 0..159
  const int b = row >> 11, t = row & 2047;
  const int g = u / 40;
  const int r = u - g * 40;
  const int slot = r >> 3;       // 0..4
  const int d0 = (r & 7) * 8;    // 0..56 (lower half)

  const bf16_t* src = qkv + (size_t)row * 3072 + g * 768 + slot * 128 + d0;
  short lo[8], hi[8];
  *reinterpret_cast<uint4*>(lo) = *reinterpret_cast<const uint4*>(src);
  *reinterpret_cast<uint4*>(hi) = *reinterpret_cast<const uint4*>(src + 64);
  float4 c0 = *reinterpret_cast<const float4*>(cosp + t * 128 + d0);
  float4 c1 = *reinterpret_cast<const float4*>(cosp + t * 128 + d0 + 4);
  float4 s0 = *reinterpret_cast<const float4*>(sinp + t * 128 + d0);
  float4 s1 = *reinterpret_cast<const float4*>(sinp + t * 128 + d0 + 4);
  float cs[8] = {c0.x, c0.y, c0.z, c0.w, c1.x, c1.y, c1.z, c1.w};
  float sn[8] = {s0.x, s0.y, s0.z, s0.w, s1.x, s1.y, s1.z, s1.w};

  const bool isq = (slot < 4);
  const float scale = isq ? (0.08838834764831843f * 1.4426950408889634f) : 1.0f;

  bf16_t olo[8], ohi[8];
#pragma unroll
  for (int e = 0; e < 8; ++e) {
    float x1 = __bfloat162float(*reinterpret_cast<const bf16_t*>(&lo[e]));
    float x2 = __bfloat162float(*reinterpret_cast<const bf16_t*>(&hi[e]));
    olo[e] = __float2bfloat16((x1 * cs[e] - x2 * sn[e]) * scale);
    ohi[e] = __float2bfloat16((x2 * cs[e] + x1 * sn[e]) * scale);
  }

  bf16_t* dst;
  if (isq) {
    int h = g * 4 + slot;
    dst = Q + (((size_t)(b * 16 + h)) * 2048 + t) * 128 + d0;
  } else {
    dst = K + (((size_t)(b * 4 + g)) * 2048 + t) * 128 + d0;
  }
  *reinterpret_cast<uint4*>(dst) = *reinterpret_cast<const uint4*>(olo);
  *reinterpret_cast<uint4*>(dst + 64) = *reinterpret_cast<const uint4*>(ohi);
}

// ---------------- V slice of qkv [b*t][g*768+640+d] -> Vt [bg][d][t] -----
__global__ void transpose_v2(const bf16_t* __restrict__ qkv, bf16_t* __restrict__ Vt) {
  __shared__ bf16_t tile[32][33];
  const int bg = blockIdx.z;
  const int b = bg >> 2, g = bg & 3;
  const int t0 = blockIdx.x * 32;
  const int d0 = blockIdx.y * 32;
  const bf16_t* src = qkv + (size_t)b * 2048 * 3072 + g * 768 + 640;
  bf16_t* dst = Vt + (size_t)bg * 128 * 2048;
#pragma unroll
  for (int i = threadIdx.y; i < 32; i += 8)
    tile[i][threadIdx.x] = src[(size_t)(t0 + i) * 3072 + d0 + threadIdx.x];
  __syncthreads();
#pragma unroll
  for (int i = threadIdx.y; i < 32; i += 8)
    dst[(size_t)(d0 + i) * 2048 + t0 + threadIdx.x] = tile[threadIdx.x][i];
}

// ---------------- sliding-window flash attention (v10, plateau) ----------
#define VROW 40
__global__ __launch_bounds__(256) void attn_swa(const bf16_t* __restrict__ Q,
                                                const bf16_t* __restrict__ K,
                                                const bf16_t* __restrict__ Vt,
                                                bf16_t* __restrict__ Y) {
  __shared__ __align__(16) bf16_t Ks[2 * 32 * 128];
  __shared__ __align__(16) bf16_t Vs[2 * 128 * VROW];

  const int tid = threadIdx.x;
  const int lane = tid & 63;
  const int w = tid >> 6;
  const int lr = lane & 15, lc = lane >> 4;
  const int b = blockIdx.z, h = blockIdx.y;
  const int g = h >> 2;

  int nseg, sx0, sx1 = 0;
  if (blockIdx.x < 16) {
    nseg = 1;
    sx0 = blockIdx.x + 16;
  } else {
    nseg = 2;
    sx0 = blockIdx.x - 16;
    sx1 = 15 - sx0;
  }

  const bf16_t* Qp = Q + ((size_t)(b * 16 + h) * 2048) * 128;
  const bf16_t* Kp = K + ((size_t)(b * 4 + g) * 2048) * 128;
  const bf16_t* Vp = Vt + ((size_t)(b * 4 + g) * 128) * 2048;

  const int kmj = tid >> 4;
  const int kmc = ((tid & 15) ^ (kmj & 7)) * 8;
  const bf16_t* Ksrc = Kp + (size_t)kmj * 128 + kmc;
  const int vd = tid >> 2, vc = tid & 3;
  const bf16_t* Vsrc = Vp + (size_t)vd * 2048 + vc * 8;
  const int vdst = vd * VROW + (vc & 1) * 16 + (vc >> 1) * 4;

  auto loadK = [&](int j0, uint4& ka, uint4& kb) {
    const bf16_t* s = Ksrc + (size_t)j0 * 128;
    ka = *reinterpret_cast<const uint4*>(s);
    kb = *reinterpret_cast<const uint4*>(s + 16 * 128);
  };
  auto writeK = [&](int bufi, uint4 ka, uint4 kb) {
    *reinterpret_cast<uint4*>(Ks + bufi * 4096 + tid * 8) = ka;
    *reinterpret_cast<uint4*>(Ks + bufi * 4096 + 2048 + tid * 8) = kb;
  };
  auto loadV = [&](int j0, uint4& a, uint4& bqv) {
    a = *reinterpret_cast<const uint4*>(Vsrc + j0);
    bqv = *reinterpret_cast<const uint4*>(Vsrc + 64 * 2048 + j0);
  };
  auto writeV = [&](int bufi, uint4 a, uint4 bqv) {
    bf16_t* p = Vs + bufi * 128 * VROW + vdst;
    *reinterpret_cast<uint2*>(p) = make_uint2(a.x, a.y);
    *reinterpret_cast<uint2*>(p + 8) = make_uint2(a.z, a.w);
    bf16_t* p1 = p + 64 * VROW;
    *reinterpret_cast<uint2*>(p1) = make_uint2(bqv.x, bqv.y);
    *reinterpret_cast<uint2*>(p1 + 8) = make_uint2(bqv.z, bqv.w);
  };

  const int kxor = (lr & 7) << 4;

  for (int sidx = 0; sidx < nseg; ++sidx) {
    const int i0b = ((sidx == 0) ? sx0 : sx1) * 64;
    const int i0 = i0b + w * 16;
    const int qrow = i0 + lr;

    bf16x8 qf[4];
#pragma unroll
    for (int kc = 0; kc < 4; ++kc)
      qf[kc] = *reinterpret_cast<const bf16x8*>(&Qp[(size_t)qrow * 128 + kc * 32 + lc * 8]);

    f32x4 o[8] = {};
    float mrun = -1e30f, lrun = 0.f;  // lrun LANE-PARTIAL (reduced at epilogue)

    int lo = i0b - 1023;
    if (lo < 0) lo = 0;
    const int jstart = lo & ~31;
    const int jlast = i0b + 32;

    {
      uint4 ka, kb, va, vb;
      loadK(jstart, ka, kb);
      loadV(jstart, va, vb);
      writeK(0, ka, kb);
      writeV(0, va, vb);
    }
    __syncthreads();

    int buf = 0;
    for (int j0 = jstart; j0 <= jlast; j0 += 32) {
      const int nxt = j0 + 32;
      uint4 ka, kb, va, vb;
      const bool do_stage = (nxt <= jlast);
      if (do_stage) {
        loadK(nxt, ka, kb);
        loadV(nxt, va, vb);
      }

      const bool active = (j0 <= i0 + 15) && (j0 + 31 > i0 - 1024);
      if (active) {
        const bf16_t* Kb = Ks + buf * 4096;
        const bf16_t* Vb = Vs + buf * 128 * VROW;
        f32x4 s0 = {}, s1 = {};
        __builtin_amdgcn_s_setprio(1);
#pragma unroll
        for (int kc = 0; kc < 4; ++kc) {
          int col = ((kc * 64 + lc * 16) ^ kxor) >> 1;
          bf16x8 kf0 = *reinterpret_cast<const bf16x8*>(Kb + lr * 128 + col);
          bf16x8 kf1 = *reinterpret_cast<const bf16x8*>(Kb + (16 + lr) * 128 + col);
          s0 = __builtin_amdgcn_mfma_f32_16x16x32_bf16(kf0, qf[kc], s0, 0, 0, 0);
          s1 = __builtin_amdgcn_mfma_f32_16x16x32_bf16(kf1, qf[kc], s1, 0, 0, 0);
        }
        __builtin_amdgcn_s_setprio(0);
        bf16x8 vvf[8];
#pragma unroll
        for (int f = 0; f < 8; ++f)
          vvf[f] = *reinterpret_cast<const bf16x8*>(Vb + (f * 16 + lr) * VROW + lc * 8);

        const bool full = (j0 + 31 <= i0) && (j0 >= i0 - 1008);
        if (!full) {
#pragma unroll
          for (int r = 0; r < 4; ++r) {
            int ja = j0 + lc * 4 + r;
            int jb = ja + 16;
            bool oka = (ja <= qrow) && (ja > qrow - 1024);
            bool okb = (jb <= qrow) && (jb > qrow - 1024);
            s0[r] = oka ? s0[r] : -1e30f;
            s1[r] = okb ? s1[r] : -1e30f;
          }
        }
        float rm = fmaxf(fmaxf(fmaxf(s0[0], s0[1]), fmaxf(s0[2], s0[3])),
                         fmaxf(fmaxf(s1[0], s1[1]), fmaxf(s1[2], s1[3])));

        if (!__all(rm <= mrun + 11.5f)) {
          rm = fmaxf(rm, __shfl_xor(rm, 16));
          rm = fmaxf(rm, __shfl_xor(rm, 32));
          float mnew = fmaxf(mrun, rm);
          float alpha = exp2f(mrun - mnew);
          mrun = mnew;
          lrun *= alpha;
#pragma unroll
          for (int f = 0; f < 8; ++f)
#pragma unroll
            for (int r = 0; r < 4; ++r) o[f][r] *= alpha;
        }

        float p0[4], p1[4], ps = 0.f;
#pragma unroll
        for (int r = 0; r < 4; ++r) {
          p0[r] = exp2f(s0[r] - mrun);
          p1[r] = exp2f(s1[r] - mrun);
          ps += p0[r] + p1[r];
        }
        lrun += ps;

        bf16_t pb[8];
#pragma unroll
        for (int r = 0; r < 4; ++r) {
          pb[r] = __float2bfloat16(p0[r]);
          pb[r + 4] = __float2bfloat16(p1[r]);
        }
        bf16x8 pfrag = *reinterpret_cast<bf16x8*>(pb);

        __builtin_amdgcn_s_setprio(1);
#pragma unroll
        for (int f = 0; f < 8; ++f)
          o[f] = __builtin_amdgcn_mfma_f32_16x16x32_bf16(vvf[f], pfrag, o[f], 0, 0, 0);
        __builtin_amdgcn_s_setprio(0);
      }

      if (do_stage) {
        writeK(buf ^ 1, ka, kb);
        writeV(buf ^ 1, va, vb);
      }
      __syncthreads();
      buf ^= 1;
    }

    float lt = lrun;
    lt += __shfl_xor(lt, 16);
    lt += __shfl_xor(lt, 32);
    float inv = 1.f / lt;
#pragma unroll
    for (int f = 0; f < 8; ++f) {
      bf16_t ob[4];
#pragma unroll
      for (int r = 0; r < 4; ++r) ob[r] = __float2bfloat16(o[f][r] * inv);
      *reinterpret_cast<uint2*>(
          &Y[((size_t)(b * 2048 + qrow)) * 2048 + h * 128 + f * 16 + lc * 4]) =
          *reinterpret_cast<uint2*>(ob);
    }
  }
}

// ---------------- launch ----------------
extern "C" void kernel_launch(void* const* d_in, const int* in_sizes, int n_in,
                              void* d_out, int out_size, void* d_ws, size_t ws_size,
                              hipStream_t stream) {
  const float* x = (const float*)d_in[0];
  const float* cosp = (const float*)d_in[1];
  const float* sinp = (const float*)d_in[2];
  const float* Wa = (const float*)d_in[3];
  const float* Wp = (const float*)d_in[4];
  float* out = (float*)d_out;

  bf16_t* ws = (bf16_t*)d_ws;
  bf16_t* xb = ws;                  // x bf16 -> reused as Q
  bf16_t* wab = ws + 8388608;       // W_attn bf16 -> reused as K
  bf16_t* wpb = ws + 14680064;      // W_proj bf16
  bf16_t* qkv = ws + 18874368;      // qkv bf16 -> reused as Y,Vt
  bf16_t* Q = xb;                   // [B][H][T][HS]
  bf16_t* Kr = wab;                 // [B][G][T][HS]
  bf16_t* Y = qkv;                  // [B][T][H][HS]
  bf16_t* Vt = qkv + 8388608;       // [B][G][HS][T]

  // fused converts: 2359296 groups of 8 = x(1048576) + Wa(786432) + Wp(524288)
  cvt3<<<9216, 256, 0, stream>>>(x, Wa, Wp, xb, wab, wpb);

  // qkv = xb @ wab^T : M=4096 N=3072 K=2048  (BN=192 -> 256 blocks)
  gemm256<192, bf16_t><<<dim3(16, 16), 512, 0, stream>>>(xb, wab, qkv, 4096, 3072, 2048);

  // RoPE Q/K only (V slice consumed by transpose_v2 straight from qkv)
  rope_qk<<<2048, 320, 0, stream>>>(qkv, cosp, sinp, Q, Kr);

  transpose_v2<<<dim3(64, 4, 8), dim3(32, 8), 0, stream>>>(qkv, Vt);

  attn_swa<<<dim3(24, 16, 2), 256, 0, stream>>>(Q, Kr, Vt, Y);

  // out = Y @ wpb^T : M=4096 N=2048 K=2048  (BN=128 -> 256 blocks)
  gemm256<128, float><<<dim3(16, 16), 512, 0, stream>>>(Y, wpb, out, 4096, 2048, 2048);
}

// Round 18
// 202.108 us; speedup vs baseline: 1.1153x; 1.0864x over previous
//
#include <hip/hip_runtime.h>
#include <hip/hip_bf16.h>
#include <cstdint>
#include <type_traits>

using bf16_t = __hip_bfloat16;
typedef __bf16 bf16x8 __attribute__((ext_vector_type(8)));
typedef float f32x4 __attribute__((ext_vector_type(4)));

typedef __attribute__((address_space(3))) uint32_t lds_u32_t;
typedef const __attribute__((address_space(1))) uint32_t glb_u32_t;

// ---------------- fused f32 -> bf16 convert (x, W_attn, W_proj) ----------
__global__ void cvt3(const float* __restrict__ x, const float* __restrict__ wa,
                     const float* __restrict__ wp, bf16_t* __restrict__ xb,
                     bf16_t* __restrict__ wab, bf16_t* __restrict__ wpb) {
  int i = blockIdx.x * blockDim.x + threadIdx.x;  // group of 8 elems
  const float* src;
  bf16_t* dst;
  int off;
  if (i < 1048576) {
    src = x; dst = xb; off = i;
  } else if (i < 1835008) {
    src = wa; dst = wab; off = i - 1048576;
  } else {
    src = wp; dst = wpb; off = i - 1835008;
  }
  const float4* p = reinterpret_cast<const float4*>(src) + (size_t)off * 2;
  float4 a = p[0];
  float4 b = p[1];
  bf16_t o[8];
  o[0] = __float2bfloat16(a.x); o[1] = __float2bfloat16(a.y);
  o[2] = __float2bfloat16(a.z); o[3] = __float2bfloat16(a.w);
  o[4] = __float2bfloat16(b.x); o[5] = __float2bfloat16(b.y);
  o[6] = __float2bfloat16(b.z); o[7] = __float2bfloat16(b.w);
  *reinterpret_cast<uint4*>(dst + (size_t)off * 8) = *reinterpret_cast<const uint4*>(o);
}

// ---------------- bf16 GEMM, 256xBN tile, counted-vmcnt pipeline ---------
// (round-13/15 form -- confirmed local optimum: r14/r16/r17 variants all
// regressed). 512 thr = 8 waves (2M x 4N), per-wave 128 x BN/4 output,
// BK=64, LDS dbuf, grid = 256 blocks = 1/CU. 1-tile-lag counted waits;
// never vmcnt(0) in steady state. T2 swizzle via pre-swizzled source +
// swizzled ds_read. T1 bijective XCD swizzle. Further headroom is L3-BW
// (panel re-fetch ~470/386 MB at ~9 TB/s), not schedule.
template <int BN, typename OutT>
__global__ __launch_bounds__(512, 2) void gemm256(const bf16_t* __restrict__ A,
                                                  const bf16_t* __restrict__ Bt,
                                                  OutT* __restrict__ C,
                                                  int M, int N, int K) {
  constexpr int JN = BN / 64;
  constexpr int BL = BN / 64;
  __shared__ __align__(16) bf16_t As[2 * 256 * 64];
  __shared__ __align__(16) bf16_t Bs[2 * BN * 64];
  const int tid = threadIdx.x;
  const int lane = tid & 63;
  const int w = tid >> 6;
  const int wm = w >> 2, wn = w & 3;
  const int lr = lane & 15, lc = lane >> 4;

  const int nwg = gridDim.x * gridDim.y;
  const int orig = blockIdx.y * gridDim.x + blockIdx.x;
  const int cpx = nwg >> 3;
  const int swz = (orig & 7) * cpx + (orig >> 3);
  const int bx = swz % gridDim.x, by = swz / gridDim.x;
  const int m0 = by * 256, n0 = bx * BN;

  const int srow = tid >> 3;
  const int scol = ((tid & 7) ^ (srow & 7)) * 8;
  const bf16_t* Asrc = A + (size_t)(m0 + srow) * K + scol;
  const bf16_t* Bsrc = Bt + (size_t)(n0 + srow) * K + scol;

  f32x4 acc[8][JN] = {};

  auto stageA = [&](int bufi, int kt) {
#pragma unroll
    for (int l = 0; l < 4; ++l)
      __builtin_amdgcn_global_load_lds(
          (glb_u32_t*)(Asrc + (size_t)kt * 64 + (size_t)l * 64 * K),
          (lds_u32_t*)(As + bufi * 16384 + l * 4096 + w * 512), 16, 0, 0);
  };
  auto stageB = [&](int bufi, int kt) {
#pragma unroll
    for (int l = 0; l < BL; ++l)
      __builtin_amdgcn_global_load_lds(
          (glb_u32_t*)(Bsrc + (size_t)kt * 64 + (size_t)l * 64 * K),
          (lds_u32_t*)(Bs + bufi * BN * 64 + l * 4096 + w * 512), 16, 0, 0);
  };

  const int nt = K >> 6;
  stageA(0, 0);
  stageB(0, 0);

  bf16x8 a[8][2], bb[JN][2];
  for (int t = 0; t < nt; ++t) {
    const int buf = t & 1;
    const char* Ab = (const char*)(As + buf * 16384);
    const char* Bb = (const char*)(Bs + buf * BN * 64);
    const bool st = (t + 1 < nt);

    auto rdA = [&](int i, int kk) {
      int R = wm * 128 + i * 16 + lr;
      return *reinterpret_cast<const bf16x8*>(
          Ab + R * 128 + ((kk * 64 + lc * 16) ^ ((R & 7) << 4)));
    };
    auto rdB = [&](int j, int kk) {
      int R = wn * (BN / 4) + j * 16 + lr;
      return *reinterpret_cast<const bf16x8*>(
          Bb + R * 128 + ((kk * 64 + lc * 16) ^ ((R & 7) << 4)));
    };

    // phase A: own A(t) landed (issued a full tile ago); B(t) in flight.
    if constexpr (BL == 3) {
      asm volatile("s_waitcnt vmcnt(3)" ::: "memory");
    } else {
      asm volatile("s_waitcnt vmcnt(2)" ::: "memory");
    }
    __builtin_amdgcn_s_barrier();
#pragma unroll
    for (int i = 0; i < 8; ++i) { a[i][0] = rdA(i, 0); a[i][1] = rdA(i, 1); }
    if (st) stageA(buf ^ 1, t + 1);

    // phase B: own B(t) landed; A(t+1) stays in flight (count 4).
    if (st) {
      asm volatile("s_waitcnt vmcnt(4)" ::: "memory");
    } else {
      asm volatile("s_waitcnt vmcnt(0)" ::: "memory");
    }
    __builtin_amdgcn_s_barrier();
#pragma unroll
    for (int j = 0; j < JN; ++j) { bb[j][0] = rdB(j, 0); bb[j][1] = rdB(j, 1); }
    if (st) stageB(buf ^ 1, t + 1);

    __builtin_amdgcn_s_setprio(1);
#pragma unroll
    for (int i = 0; i < 8; ++i)
#pragma unroll
      for (int j = 0; j < JN; ++j) {
        acc[i][j] = __builtin_amdgcn_mfma_f32_16x16x32_bf16(a[i][0], bb[j][0], acc[i][j], 0, 0, 0);
        acc[i][j] = __builtin_amdgcn_mfma_f32_16x16x32_bf16(a[i][1], bb[j][1], acc[i][j], 0, 0, 0);
      }
    __builtin_amdgcn_s_setprio(0);
  }

  // epilogue: C/D layout col=lane&15, row=(lane>>4)*4+reg  [m89/m91]
#pragma unroll
  for (int i = 0; i < 8; ++i)
#pragma unroll
    for (int j = 0; j < JN; ++j) {
      int row = m0 + wm * 128 + i * 16 + lc * 4;
      int col = n0 + wn * (BN / 4) + j * 16 + lr;
#pragma unroll
      for (int r = 0; r < 4; ++r) {
        float v = acc[i][j][r];
        if constexpr (std::is_same<OutT, float>::value)
          C[(size_t)(row + r) * N + col] = v;
        else
          C[(size_t)(row + r) * N + col] = __float2bfloat16(v);
      }
    }
}

// ---------------- fused RoPE(Q,K) + V-transpose, one dispatch ------------
// Blocks 0..2047: rope (2 rows x 160 pair-units, 320 threads, no idle).
// Blocks 2048..4095: V-slice transpose qkv -> Vt (first 256 threads).
__global__ __launch_bounds__(320) void rope_tv(const bf16_t* __restrict__ qkv,
                                               const float* __restrict__ cosp,
                                               const float* __restrict__ sinp,
                                               bf16_t* __restrict__ Q,
                                               bf16_t* __restrict__ K,
                                               bf16_t* __restrict__ Vt) {
  if (blockIdx.x < 2048) {
    const int row = blockIdx.x * 2 + (threadIdx.x >= 160 ? 1 : 0);
    const int u = threadIdx.x >= 160 ? threadIdx.x - 160 : threadIdx.x;  // 0..159
    const int b = row >> 11, t = row & 2047;
    const int g = u / 40;
    const int r = u - g * 40;
    const int slot = r >> 3;     // 0..4
    const int d0 = (r & 7) * 8;  // 0..56 (lower half)

    const bf16_t* src = qkv + (size_t)row * 3072 + g * 768 + slot * 128 + d0;
    short lo[8], hi[8];
    *reinterpret_cast<uint4*>(lo) = *reinterpret_cast<const uint4*>(src);
    *reinterpret_cast<uint4*>(hi) = *reinterpret_cast<const uint4*>(src + 64);
    float4 c0 = *reinterpret_cast<const float4*>(cosp + t * 128 + d0);
    float4 c1 = *reinterpret_cast<const float4*>(cosp + t * 128 + d0 + 4);
    float4 s0 = *reinterpret_cast<const float4*>(sinp + t * 128 + d0);
    float4 s1 = *reinterpret_cast<const float4*>(sinp + t * 128 + d0 + 4);
    float cs[8] = {c0.x, c0.y, c0.z, c0.w, c1.x, c1.y, c1.z, c1.w};
    float sn[8] = {s0.x, s0.y, s0.z, s0.w, s1.x, s1.y, s1.z, s1.w};

    const bool isq = (slot < 4);
    // Q gets softmax scale 1/sqrt(128) * log2(e) folded (attn uses exp2)
    const float scale = isq ? (0.08838834764831843f * 1.4426950408889634f) : 1.0f;

    bf16_t olo[8], ohi[8];
#pragma unroll
    for (int e = 0; e < 8; ++e) {
      float x1 = __bfloat162float(*reinterpret_cast<const bf16_t*>(&lo[e]));
      float x2 = __bfloat162float(*reinterpret_cast<const bf16_t*>(&hi[e]));
      olo[e] = __float2bfloat16((x1 * cs[e] - x2 * sn[e]) * scale);
      ohi[e] = __float2bfloat16((x2 * cs[e] + x1 * sn[e]) * scale);
    }

    bf16_t* dst;
    if (isq) {
      int h = g * 4 + slot;
      dst = Q + (((size_t)(b * 16 + h)) * 2048 + t) * 128 + d0;
    } else {
      dst = K + (((size_t)(b * 4 + g)) * 2048 + t) * 128 + d0;
    }
    *reinterpret_cast<uint4*>(dst) = *reinterpret_cast<const uint4*>(olo);
    *reinterpret_cast<uint4*>(dst + 64) = *reinterpret_cast<const uint4*>(ohi);
  } else {
    __shared__ bf16_t tile[32][33];
    const int bid = blockIdx.x - 2048;
    const int t0 = (bid & 63) * 32;
    const int d0 = ((bid >> 6) & 3) * 32;
    const int bg = bid >> 8;
    const int b = bg >> 2, g = bg & 3;
    const bf16_t* src = qkv + (size_t)b * 2048 * 3072 + g * 768 + 640;
    bf16_t* dst = Vt + (size_t)bg * 128 * 2048;
    const int tx = threadIdx.x & 31, ty = threadIdx.x >> 5;  // ty 0..9
    if (ty < 8) {
#pragma unroll
      for (int i = ty; i < 32; i += 8)
        tile[i][tx] = src[(size_t)(t0 + i) * 3072 + d0 + tx];
    }
    __syncthreads();
    if (ty < 8) {
#pragma unroll
      for (int i = ty; i < 32; i += 8)
        dst[(size_t)(d0 + i) * 2048 + t0 + tx] = tile[tx][i];
    }
  }
}

// ---------------- sliding-window flash attention (v10, plateau) ----------
#define VROW 40
__global__ __launch_bounds__(256) void attn_swa(const bf16_t* __restrict__ Q,
                                                const bf16_t* __restrict__ K,
                                                const bf16_t* __restrict__ Vt,
                                                bf16_t* __restrict__ Y) {
  __shared__ __align__(16) bf16_t Ks[2 * 32 * 128];
  __shared__ __align__(16) bf16_t Vs[2 * 128 * VROW];

  const int tid = threadIdx.x;
  const int lane = tid & 63;
  const int w = tid >> 6;
  const int lr = lane & 15, lc = lane >> 4;
  const int b = blockIdx.z, h = blockIdx.y;
  const int g = h >> 2;

  int nseg, sx0, sx1 = 0;
  if (blockIdx.x < 16) {
    nseg = 1;
    sx0 = blockIdx.x + 16;
  } else {
    nseg = 2;
    sx0 = blockIdx.x - 16;
    sx1 = 15 - sx0;
  }

  const bf16_t* Qp = Q + ((size_t)(b * 16 + h) * 2048) * 128;
  const bf16_t* Kp = K + ((size_t)(b * 4 + g) * 2048) * 128;
  const bf16_t* Vp = Vt + ((size_t)(b * 4 + g) * 128) * 2048;

  const int kmj = tid >> 4;
  const int kmc = ((tid & 15) ^ (kmj & 7)) * 8;
  const bf16_t* Ksrc = Kp + (size_t)kmj * 128 + kmc;
  const int vd = tid >> 2, vc = tid & 3;
  const bf16_t* Vsrc = Vp + (size_t)vd * 2048 + vc * 8;
  const int vdst = vd * VROW + (vc & 1) * 16 + (vc >> 1) * 4;

  auto loadK = [&](int j0, uint4& ka, uint4& kb) {
    const bf16_t* s = Ksrc + (size_t)j0 * 128;
    ka = *reinterpret_cast<const uint4*>(s);
    kb = *reinterpret_cast<const uint4*>(s + 16 * 128);
  };
  auto writeK = [&](int bufi, uint4 ka, uint4 kb) {
    *reinterpret_cast<uint4*>(Ks + bufi * 4096 + tid * 8) = ka;
    *reinterpret_cast<uint4*>(Ks + bufi * 4096 + 2048 + tid * 8) = kb;
  };
  auto loadV = [&](int j0, uint4& a, uint4& bqv) {
    a = *reinterpret_cast<const uint4*>(Vsrc + j0);
    bqv = *reinterpret_cast<const uint4*>(Vsrc + 64 * 2048 + j0);
  };
  auto writeV = [&](int bufi, uint4 a, uint4 bqv) {
    bf16_t* p = Vs + bufi * 128 * VROW + vdst;
    *reinterpret_cast<uint2*>(p) = make_uint2(a.x, a.y);
    *reinterpret_cast<uint2*>(p + 8) = make_uint2(a.z, a.w);
    bf16_t* p1 = p + 64 * VROW;
    *reinterpret_cast<uint2*>(p1) = make_uint2(bqv.x, bqv.y);
    *reinterpret_cast<uint2*>(p1 + 8) = make_uint2(bqv.z, bqv.w);
  };

  const int kxor = (lr & 7) << 4;

  for (int sidx = 0; sidx < nseg; ++sidx) {
    const int i0b = ((sidx == 0) ? sx0 : sx1) * 64;
    const int i0 = i0b + w * 16;
    const int qrow = i0 + lr;

    bf16x8 qf[4];
#pragma unroll
    for (int kc = 0; kc < 4; ++kc)
      qf[kc] = *reinterpret_cast<const bf16x8*>(&Qp[(size_t)qrow * 128 + kc * 32 + lc * 8]);

    f32x4 o[8] = {};
    float mrun = -1e30f, lrun = 0.f;  // lrun LANE-PARTIAL (reduced at epilogue)

    int lo = i0b - 1023;
    if (lo < 0) lo = 0;
    const int jstart = lo & ~31;
    const int jlast = i0b + 32;

    {
      uint4 ka, kb, va, vb;
      loadK(jstart, ka, kb);
      loadV(jstart, va, vb);
      writeK(0, ka, kb);
      writeV(0, va, vb);
    }
    __syncthreads();

    int buf = 0;
    for (int j0 = jstart; j0 <= jlast; j0 += 32) {
      const int nxt = j0 + 32;
      uint4 ka, kb, va, vb;
      const bool do_stage = (nxt <= jlast);
      if (do_stage) {
        loadK(nxt, ka, kb);
        loadV(nxt, va, vb);
      }

      const bool active = (j0 <= i0 + 15) && (j0 + 31 > i0 - 1024);
      if (active) {
        const bf16_t* Kb = Ks + buf * 4096;
        const bf16_t* Vb = Vs + buf * 128 * VROW;
        f32x4 s0 = {}, s1 = {};
        __builtin_amdgcn_s_setprio(1);
#pragma unroll
        for (int kc = 0; kc < 4; ++kc) {
          int col = ((kc * 64 + lc * 16) ^ kxor) >> 1;
          bf16x8 kf0 = *reinterpret_cast<const bf16x8*>(Kb + lr * 128 + col);
          bf16x8 kf1 = *reinterpret_cast<const bf16x8*>(Kb + (16 + lr) * 128 + col);
          s0 = __builtin_amdgcn_mfma_f32_16x16x32_bf16(kf0, qf[kc], s0, 0, 0, 0);
          s1 = __builtin_amdgcn_mfma_f32_16x16x32_bf16(kf1, qf[kc], s1, 0, 0, 0);
        }
        __builtin_amdgcn_s_setprio(0);
        bf16x8 vvf[8];
#pragma unroll
        for (int f = 0; f < 8; ++f)
          vvf[f] = *reinterpret_cast<const bf16x8*>(Vb + (f * 16 + lr) * VROW + lc * 8);

        const bool full = (j0 + 31 <= i0) && (j0 >= i0 - 1008);
        if (!full) {
#pragma unroll
          for (int r = 0; r < 4; ++r) {
            int ja = j0 + lc * 4 + r;
            int jb = ja + 16;
            bool oka = (ja <= qrow) && (ja > qrow - 1024);
            bool okb = (jb <= qrow) && (jb > qrow - 1024);
            s0[r] = oka ? s0[r] : -1e30f;
            s1[r] = okb ? s1[r] : -1e30f;
          }
        }
        float rm = fmaxf(fmaxf(fmaxf(s0[0], s0[1]), fmaxf(s0[2], s0[3])),
                         fmaxf(fmaxf(s1[0], s1[1]), fmaxf(s1[2], s1[3])));

        if (!__all(rm <= mrun + 11.5f)) {
          rm = fmaxf(rm, __shfl_xor(rm, 16));
          rm = fmaxf(rm, __shfl_xor(rm, 32));
          float mnew = fmaxf(mrun, rm);
          float alpha = exp2f(mrun - mnew);
          mrun = mnew;
          lrun *= alpha;
#pragma unroll
          for (int f = 0; f < 8; ++f)
#pragma unroll
            for (int r = 0; r < 4; ++r) o[f][r] *= alpha;
        }

        float p0[4], p1[4], ps = 0.f;
#pragma unroll
        for (int r = 0; r < 4; ++r) {
          p0[r] = exp2f(s0[r] - mrun);
          p1[r] = exp2f(s1[r] - mrun);
          ps += p0[r] + p1[r];
        }
        lrun += ps;

        bf16_t pb[8];
#pragma unroll
        for (int r = 0; r < 4; ++r) {
          pb[r] = __float2bfloat16(p0[r]);
          pb[r + 4] = __float2bfloat16(p1[r]);
        }
        bf16x8 pfrag = *reinterpret_cast<bf16x8*>(pb);

        __builtin_amdgcn_s_setprio(1);
#pragma unroll
        for (int f = 0; f < 8; ++f)
          o[f] = __builtin_amdgcn_mfma_f32_16x16x32_bf16(vvf[f], pfrag, o[f], 0, 0, 0);
        __builtin_amdgcn_s_setprio(0);
      }

      if (do_stage) {
        writeK(buf ^ 1, ka, kb);
        writeV(buf ^ 1, va, vb);
      }
      __syncthreads();
      buf ^= 1;
    }

    float lt = lrun;
    lt += __shfl_xor(lt, 16);
    lt += __shfl_xor(lt, 32);
    float inv = 1.f / lt;
#pragma unroll
    for (int f = 0; f < 8; ++f) {
      bf16_t ob[4];
#pragma unroll
      for (int r = 0; r < 4; ++r) ob[r] = __float2bfloat16(o[f][r] * inv);
      *reinterpret_cast<uint2*>(
          &Y[((size_t)(b * 2048 + qrow)) * 2048 + h * 128 + f * 16 + lc * 4]) =
          *reinterpret_cast<uint2*>(ob);
    }
  }
}

// ---------------- launch ----------------
extern "C" void kernel_launch(void* const* d_in, const int* in_sizes, int n_in,
                              void* d_out, int out_size, void* d_ws, size_t ws_size,
                              hipStream_t stream) {
  const float* x = (const float*)d_in[0];
  const float* cosp = (const float*)d_in[1];
  const float* sinp = (const float*)d_in[2];
  const float* Wa = (const float*)d_in[3];
  const float* Wp = (const float*)d_in[4];
  float* out = (float*)d_out;

  bf16_t* ws = (bf16_t*)d_ws;
  bf16_t* xb = ws;                  // x bf16 -> reused as Q
  bf16_t* wab = ws + 8388608;       // W_attn bf16 -> reused as K
  bf16_t* wpb = ws + 14680064;      // W_proj bf16
  bf16_t* qkv = ws + 18874368;      // qkv bf16 -> reused as Y,Vt
  bf16_t* Q = xb;                   // [B][H][T][HS]
  bf16_t* Kr = wab;                 // [B][G][T][HS]
  bf16_t* Y = qkv;                  // [B][T][H][HS]
  bf16_t* Vt = qkv + 8388608;       // [B][G][HS][T]

  // fused converts: 2359296 groups of 8 = x(1048576) + Wa(786432) + Wp(524288)
  cvt3<<<9216, 256, 0, stream>>>(x, Wa, Wp, xb, wab, wpb);

  // qkv = xb @ wab^T : M=4096 N=3072 K=2048  (BN=192 -> 256 blocks)
  gemm256<192, bf16_t><<<dim3(16, 16), 512, 0, stream>>>(xb, wab, qkv, 4096, 3072, 2048);

  // fused RoPE(Q,K) + V transpose (one dispatch, independent block families)
  rope_tv<<<4096, 320, 0, stream>>>(qkv, cosp, sinp, Q, Kr, Vt);

  attn_swa<<<dim3(24, 16, 2), 256, 0, stream>>>(Q, Kr, Vt, Y);

  // out = Y @ wpb^T : M=4096 N=2048 K=2048  (BN=128 -> 256 blocks)
  gemm256<128, float><<<dim3(16, 16), 512, 0, stream>>>(Y, wpb, out, 4096, 2048, 2048);
}

// Round 19
// 200.736 us; speedup vs baseline: 1.1229x; 1.0068x over previous
//
#include <hip/hip_runtime.h>
#include <hip/hip_bf16.h>
#include <cstdint>
#include <type_traits>

using bf16_t = __hip_bfloat16;
typedef __bf16 bf16x8 __attribute__((ext_vector_type(8)));
typedef float f32x4 __attribute__((ext_vector_type(4)));

typedef __attribute__((address_space(3))) uint32_t lds_u32_t;
typedef const __attribute__((address_space(1))) uint32_t glb_u32_t;

// ---------------- fused f32 -> bf16 convert (x, W_attn, W_proj) ----------
__global__ void cvt3(const float* __restrict__ x, const float* __restrict__ wa,
                     const float* __restrict__ wp, bf16_t* __restrict__ xb,
                     bf16_t* __restrict__ wab, bf16_t* __restrict__ wpb) {
  int i = blockIdx.x * blockDim.x + threadIdx.x;  // group of 8 elems
  const float* src;
  bf16_t* dst;
  int off;
  if (i < 1048576) {
    src = x; dst = xb; off = i;
  } else if (i < 1835008) {
    src = wa; dst = wab; off = i - 1048576;
  } else {
    src = wp; dst = wpb; off = i - 1835008;
  }
  const float4* p = reinterpret_cast<const float4*>(src) + (size_t)off * 2;
  float4 a = p[0];
  float4 b = p[1];
  bf16_t o[8];
  o[0] = __float2bfloat16(a.x); o[1] = __float2bfloat16(a.y);
  o[2] = __float2bfloat16(a.z); o[3] = __float2bfloat16(a.w);
  o[4] = __float2bfloat16(b.x); o[5] = __float2bfloat16(b.y);
  o[6] = __float2bfloat16(b.z); o[7] = __float2bfloat16(b.w);
  *reinterpret_cast<uint4*>(dst + (size_t)off * 8) = *reinterpret_cast<const uint4*>(o);
}

// ---------------- bf16 GEMM, 256xBN tile, counted-vmcnt pipeline ---------
// (round-13/15 form -- confirmed local optimum: r14/r16/r17 variants all
// regressed). 512 thr = 8 waves (2M x 4N), per-wave 128 x BN/4 output,
// BK=64, LDS dbuf, grid = 256 blocks = 1/CU. 1-tile-lag counted waits;
// never vmcnt(0) in steady state. T2 swizzle via pre-swizzled source +
// swizzled ds_read. T1 bijective XCD swizzle.
template <int BN, typename OutT>
__global__ __launch_bounds__(512, 2) void gemm256(const bf16_t* __restrict__ A,
                                                  const bf16_t* __restrict__ Bt,
                                                  OutT* __restrict__ C,
                                                  int M, int N, int K) {
  constexpr int JN = BN / 64;
  constexpr int BL = BN / 64;
  __shared__ __align__(16) bf16_t As[2 * 256 * 64];
  __shared__ __align__(16) bf16_t Bs[2 * BN * 64];
  const int tid = threadIdx.x;
  const int lane = tid & 63;
  const int w = tid >> 6;
  const int wm = w >> 2, wn = w & 3;
  const int lr = lane & 15, lc = lane >> 4;

  const int nwg = gridDim.x * gridDim.y;
  const int orig = blockIdx.y * gridDim.x + blockIdx.x;
  const int cpx = nwg >> 3;
  const int swz = (orig & 7) * cpx + (orig >> 3);
  const int bx = swz % gridDim.x, by = swz / gridDim.x;
  const int m0 = by * 256, n0 = bx * BN;

  const int srow = tid >> 3;
  const int scol = ((tid & 7) ^ (srow & 7)) * 8;
  const bf16_t* Asrc = A + (size_t)(m0 + srow) * K + scol;
  const bf16_t* Bsrc = Bt + (size_t)(n0 + srow) * K + scol;

  f32x4 acc[8][JN] = {};

  auto stageA = [&](int bufi, int kt) {
#pragma unroll
    for (int l = 0; l < 4; ++l)
      __builtin_amdgcn_global_load_lds(
          (glb_u32_t*)(Asrc + (size_t)kt * 64 + (size_t)l * 64 * K),
          (lds_u32_t*)(As + bufi * 16384 + l * 4096 + w * 512), 16, 0, 0);
  };
  auto stageB = [&](int bufi, int kt) {
#pragma unroll
    for (int l = 0; l < BL; ++l)
      __builtin_amdgcn_global_load_lds(
          (glb_u32_t*)(Bsrc + (size_t)kt * 64 + (size_t)l * 64 * K),
          (lds_u32_t*)(Bs + bufi * BN * 64 + l * 4096 + w * 512), 16, 0, 0);
  };

  const int nt = K >> 6;
  stageA(0, 0);
  stageB(0, 0);

  bf16x8 a[8][2], bb[JN][2];
  for (int t = 0; t < nt; ++t) {
    const int buf = t & 1;
    const char* Ab = (const char*)(As + buf * 16384);
    const char* Bb = (const char*)(Bs + buf * BN * 64);
    const bool st = (t + 1 < nt);

    auto rdA = [&](int i, int kk) {
      int R = wm * 128 + i * 16 + lr;
      return *reinterpret_cast<const bf16x8*>(
          Ab + R * 128 + ((kk * 64 + lc * 16) ^ ((R & 7) << 4)));
    };
    auto rdB = [&](int j, int kk) {
      int R = wn * (BN / 4) + j * 16 + lr;
      return *reinterpret_cast<const bf16x8*>(
          Bb + R * 128 + ((kk * 64 + lc * 16) ^ ((R & 7) << 4)));
    };

    // phase A: own A(t) landed (issued a full tile ago); B(t) in flight.
    if constexpr (BL == 3) {
      asm volatile("s_waitcnt vmcnt(3)" ::: "memory");
    } else {
      asm volatile("s_waitcnt vmcnt(2)" ::: "memory");
    }
    __builtin_amdgcn_s_barrier();
#pragma unroll
    for (int i = 0; i < 8; ++i) { a[i][0] = rdA(i, 0); a[i][1] = rdA(i, 1); }
    if (st) stageA(buf ^ 1, t + 1);

    // phase B: own B(t) landed; A(t+1) stays in flight (count 4).
    if (st) {
      asm volatile("s_waitcnt vmcnt(4)" ::: "memory");
    } else {
      asm volatile("s_waitcnt vmcnt(0)" ::: "memory");
    }
    __builtin_amdgcn_s_barrier();
#pragma unroll
    for (int j = 0; j < JN; ++j) { bb[j][0] = rdB(j, 0); bb[j][1] = rdB(j, 1); }
    if (st) stageB(buf ^ 1, t + 1);

    __builtin_amdgcn_s_setprio(1);
#pragma unroll
    for (int i = 0; i < 8; ++i)
#pragma unroll
      for (int j = 0; j < JN; ++j) {
        acc[i][j] = __builtin_amdgcn_mfma_f32_16x16x32_bf16(a[i][0], bb[j][0], acc[i][j], 0, 0, 0);
        acc[i][j] = __builtin_amdgcn_mfma_f32_16x16x32_bf16(a[i][1], bb[j][1], acc[i][j], 0, 0, 0);
      }
    __builtin_amdgcn_s_setprio(0);
  }

  // epilogue: C/D layout col=lane&15, row=(lane>>4)*4+reg  [m89/m91]
#pragma unroll
  for (int i = 0; i < 8; ++i)
#pragma unroll
    for (int j = 0; j < JN; ++j) {
      int row = m0 + wm * 128 + i * 16 + lc * 4;
      int col = n0 + wn * (BN / 4) + j * 16 + lr;
#pragma unroll
      for (int r = 0; r < 4; ++r) {
        float v = acc[i][j][r];
        if constexpr (std::is_same<OutT, float>::value)
          C[(size_t)(row + r) * N + col] = v;
        else
          C[(size_t)(row + r) * N + col] = __float2bfloat16(v);
      }
    }
}

// ---------------- fused RoPE(Q,K) + V-transpose, one dispatch ------------
// Blocks 0..2047: rope (2 rows x 160 pair-units, 320 threads, no idle).
// Blocks 2048..4095: V-slice transpose qkv -> Vt (first 256 threads).
// SAFE: Vt now lives in dead wab space (disjoint from qkv, Q, K, wpb), so
// rope reads of qkv cannot race transpose writes (r18's absmax wobble).
__global__ __launch_bounds__(320) void rope_tv(const bf16_t* __restrict__ qkv,
                                               const float* __restrict__ cosp,
                                               const float* __restrict__ sinp,
                                               bf16_t* __restrict__ Q,
                                               bf16_t* __restrict__ K,
                                               bf16_t* __restrict__ Vt) {
  if (blockIdx.x < 2048) {
    const int row = blockIdx.x * 2 + (threadIdx.x >= 160 ? 1 : 0);
    const int u = threadIdx.x >= 160 ? threadIdx.x - 160 : threadIdx.x;  // 0..159
    const int b = row >> 11, t = row & 2047;
    const int g = u / 40;
    const int r = u - g * 40;
    const int slot = r >> 3;     // 0..4
    const int d0 = (r & 7) * 8;  // 0..56 (lower half)

    const bf16_t* src = qkv + (size_t)row * 3072 + g * 768 + slot * 128 + d0;
    short lo[8], hi[8];
    *reinterpret_cast<uint4*>(lo) = *reinterpret_cast<const uint4*>(src);
    *reinterpret_cast<uint4*>(hi) = *reinterpret_cast<const uint4*>(src + 64);
    float4 c0 = *reinterpret_cast<const float4*>(cosp + t * 128 + d0);
    float4 c1 = *reinterpret_cast<const float4*>(cosp + t * 128 + d0 + 4);
    float4 s0 = *reinterpret_cast<const float4*>(sinp + t * 128 + d0);
    float4 s1 = *reinterpret_cast<const float4*>(sinp + t * 128 + d0 + 4);
    float cs[8] = {c0.x, c0.y, c0.z, c0.w, c1.x, c1.y, c1.z, c1.w};
    float sn[8] = {s0.x, s0.y, s0.z, s0.w, s1.x, s1.y, s1.z, s1.w};

    const bool isq = (slot < 4);
    // Q gets softmax scale 1/sqrt(128) * log2(e) folded (attn uses exp2)
    const float scale = isq ? (0.08838834764831843f * 1.4426950408889634f) : 1.0f;

    bf16_t olo[8], ohi[8];
#pragma unroll
    for (int e = 0; e < 8; ++e) {
      float x1 = __bfloat162float(*reinterpret_cast<const bf16_t*>(&lo[e]));
      float x2 = __bfloat162float(*reinterpret_cast<const bf16_t*>(&hi[e]));
      olo[e] = __float2bfloat16((x1 * cs[e] - x2 * sn[e]) * scale);
      ohi[e] = __float2bfloat16((x2 * cs[e] + x1 * sn[e]) * scale);
    }

    bf16_t* dst;
    if (isq) {
      int h = g * 4 + slot;
      dst = Q + (((size_t)(b * 16 + h)) * 2048 + t) * 128 + d0;
    } else {
      dst = K + (((size_t)(b * 4 + g)) * 2048 + t) * 128 + d0;
    }
    *reinterpret_cast<uint4*>(dst) = *reinterpret_cast<const uint4*>(olo);
    *reinterpret_cast<uint4*>(dst + 64) = *reinterpret_cast<const uint4*>(ohi);
  } else {
    __shared__ bf16_t tile[32][33];
    const int bid = blockIdx.x - 2048;
    const int t0 = (bid & 63) * 32;
    const int d0 = ((bid >> 6) & 3) * 32;
    const int bg = bid >> 8;
    const int b = bg >> 2, g = bg & 3;
    const bf16_t* src = qkv + (size_t)b * 2048 * 3072 + g * 768 + 640;
    bf16_t* dst = Vt + (size_t)bg * 128 * 2048;
    const int tx = threadIdx.x & 31, ty = threadIdx.x >> 5;  // ty 0..9
    if (ty < 8) {
#pragma unroll
      for (int i = ty; i < 32; i += 8)
        tile[i][tx] = src[(size_t)(t0 + i) * 3072 + d0 + tx];
    }
    __syncthreads();
    if (ty < 8) {
#pragma unroll
      for (int i = ty; i < 32; i += 8)
        dst[(size_t)(d0 + i) * 2048 + t0 + tx] = tile[tx][i];
    }
  }
}

// ---------------- sliding-window flash attention (v10, plateau) ----------
#define VROW 40
__global__ __launch_bounds__(256) void attn_swa(const bf16_t* __restrict__ Q,
                                                const bf16_t* __restrict__ K,
                                                const bf16_t* __restrict__ Vt,
                                                bf16_t* __restrict__ Y) {
  __shared__ __align__(16) bf16_t Ks[2 * 32 * 128];
  __shared__ __align__(16) bf16_t Vs[2 * 128 * VROW];

  const int tid = threadIdx.x;
  const int lane = tid & 63;
  const int w = tid >> 6;
  const int lr = lane & 15, lc = lane >> 4;
  const int b = blockIdx.z, h = blockIdx.y;
  const int g = h >> 2;

  int nseg, sx0, sx1 = 0;
  if (blockIdx.x < 16) {
    nseg = 1;
    sx0 = blockIdx.x + 16;
  } else {
    nseg = 2;
    sx0 = blockIdx.x - 16;
    sx1 = 15 - sx0;
  }

  const bf16_t* Qp = Q + ((size_t)(b * 16 + h) * 2048) * 128;
  const bf16_t* Kp = K + ((size_t)(b * 4 + g) * 2048) * 128;
  const bf16_t* Vp = Vt + ((size_t)(b * 4 + g) * 128) * 2048;

  const int kmj = tid >> 4;
  const int kmc = ((tid & 15) ^ (kmj & 7)) * 8;
  const bf16_t* Ksrc = Kp + (size_t)kmj * 128 + kmc;
  const int vd = tid >> 2, vc = tid & 3;
  const bf16_t* Vsrc = Vp + (size_t)vd * 2048 + vc * 8;
  const int vdst = vd * VROW + (vc & 1) * 16 + (vc >> 1) * 4;

  auto loadK = [&](int j0, uint4& ka, uint4& kb) {
    const bf16_t* s = Ksrc + (size_t)j0 * 128;
    ka = *reinterpret_cast<const uint4*>(s);
    kb = *reinterpret_cast<const uint4*>(s + 16 * 128);
  };
  auto writeK = [&](int bufi, uint4 ka, uint4 kb) {
    *reinterpret_cast<uint4*>(Ks + bufi * 4096 + tid * 8) = ka;
    *reinterpret_cast<uint4*>(Ks + bufi * 4096 + 2048 + tid * 8) = kb;
  };
  auto loadV = [&](int j0, uint4& a, uint4& bqv) {
    a = *reinterpret_cast<const uint4*>(Vsrc + j0);
    bqv = *reinterpret_cast<const uint4*>(Vsrc + 64 * 2048 + j0);
  };
  auto writeV = [&](int bufi, uint4 a, uint4 bqv) {
    bf16_t* p = Vs + bufi * 128 * VROW + vdst;
    *reinterpret_cast<uint2*>(p) = make_uint2(a.x, a.y);
    *reinterpret_cast<uint2*>(p + 8) = make_uint2(a.z, a.w);
    bf16_t* p1 = p + 64 * VROW;
    *reinterpret_cast<uint2*>(p1) = make_uint2(bqv.x, bqv.y);
    *reinterpret_cast<uint2*>(p1 + 8) = make_uint2(bqv.z, bqv.w);
  };

  const int kxor = (lr & 7) << 4;

  for (int sidx = 0; sidx < nseg; ++sidx) {
    const int i0b = ((sidx == 0) ? sx0 : sx1) * 64;
    const int i0 = i0b + w * 16;
    const int qrow = i0 + lr;

    bf16x8 qf[4];
#pragma unroll
    for (int kc = 0; kc < 4; ++kc)
      qf[kc] = *reinterpret_cast<const bf16x8*>(&Qp[(size_t)qrow * 128 + kc * 32 + lc * 8]);

    f32x4 o[8] = {};
    float mrun = -1e30f, lrun = 0.f;  // lrun LANE-PARTIAL (reduced at epilogue)

    int lo = i0b - 1023;
    if (lo < 0) lo = 0;
    const int jstart = lo & ~31;
    const int jlast = i0b + 32;

    {
      uint4 ka, kb, va, vb;
      loadK(jstart, ka, kb);
      loadV(jstart, va, vb);
      writeK(0, ka, kb);
      writeV(0, va, vb);
    }
    __syncthreads();

    int buf = 0;
    for (int j0 = jstart; j0 <= jlast; j0 += 32) {
      const int nxt = j0 + 32;
      uint4 ka, kb, va, vb;
      const bool do_stage = (nxt <= jlast);
      if (do_stage) {
        loadK(nxt, ka, kb);
        loadV(nxt, va, vb);
      }

      const bool active = (j0 <= i0 + 15) && (j0 + 31 > i0 - 1024);
      if (active) {
        const bf16_t* Kb = Ks + buf * 4096;
        const bf16_t* Vb = Vs + buf * 128 * VROW;
        f32x4 s0 = {}, s1 = {};
        __builtin_amdgcn_s_setprio(1);
#pragma unroll
        for (int kc = 0; kc < 4; ++kc) {
          int col = ((kc * 64 + lc * 16) ^ kxor) >> 1;
          bf16x8 kf0 = *reinterpret_cast<const bf16x8*>(Kb + lr * 128 + col);
          bf16x8 kf1 = *reinterpret_cast<const bf16x8*>(Kb + (16 + lr) * 128 + col);
          s0 = __builtin_amdgcn_mfma_f32_16x16x32_bf16(kf0, qf[kc], s0, 0, 0, 0);
          s1 = __builtin_amdgcn_mfma_f32_16x16x32_bf16(kf1, qf[kc], s1, 0, 0, 0);
        }
        __builtin_amdgcn_s_setprio(0);
        bf16x8 vvf[8];
#pragma unroll
        for (int f = 0; f < 8; ++f)
          vvf[f] = *reinterpret_cast<const bf16x8*>(Vb + (f * 16 + lr) * VROW + lc * 8);

        const bool full = (j0 + 31 <= i0) && (j0 >= i0 - 1008);
        if (!full) {
#pragma unroll
          for (int r = 0; r < 4; ++r) {
            int ja = j0 + lc * 4 + r;
            int jb = ja + 16;
            bool oka = (ja <= qrow) && (ja > qrow - 1024);
            bool okb = (jb <= qrow) && (jb > qrow - 1024);
            s0[r] = oka ? s0[r] : -1e30f;
            s1[r] = okb ? s1[r] : -1e30f;
          }
        }
        float rm = fmaxf(fmaxf(fmaxf(s0[0], s0[1]), fmaxf(s0[2], s0[3])),
                         fmaxf(fmaxf(s1[0], s1[1]), fmaxf(s1[2], s1[3])));

        if (!__all(rm <= mrun + 11.5f)) {
          rm = fmaxf(rm, __shfl_xor(rm, 16));
          rm = fmaxf(rm, __shfl_xor(rm, 32));
          float mnew = fmaxf(mrun, rm);
          float alpha = exp2f(mrun - mnew);
          mrun = mnew;
          lrun *= alpha;
#pragma unroll
          for (int f = 0; f < 8; ++f)
#pragma unroll
            for (int r = 0; r < 4; ++r) o[f][r] *= alpha;
        }

        float p0[4], p1[4], ps = 0.f;
#pragma unroll
        for (int r = 0; r < 4; ++r) {
          p0[r] = exp2f(s0[r] - mrun);
          p1[r] = exp2f(s1[r] - mrun);
          ps += p0[r] + p1[r];
        }
        lrun += ps;

        bf16_t pb[8];
#pragma unroll
        for (int r = 0; r < 4; ++r) {
          pb[r] = __float2bfloat16(p0[r]);
          pb[r + 4] = __float2bfloat16(p1[r]);
        }
        bf16x8 pfrag = *reinterpret_cast<bf16x8*>(pb);

        __builtin_amdgcn_s_setprio(1);
#pragma unroll
        for (int f = 0; f < 8; ++f)
          o[f] = __builtin_amdgcn_mfma_f32_16x16x32_bf16(vvf[f], pfrag, o[f], 0, 0, 0);
        __builtin_amdgcn_s_setprio(0);
      }

      if (do_stage) {
        writeK(buf ^ 1, ka, kb);
        writeV(buf ^ 1, va, vb);
      }
      __syncthreads();
      buf ^= 1;
    }

    float lt = lrun;
    lt += __shfl_xor(lt, 16);
    lt += __shfl_xor(lt, 32);
    float inv = 1.f / lt;
#pragma unroll
    for (int f = 0; f < 8; ++f) {
      bf16_t ob[4];
#pragma unroll
      for (int r = 0; r < 4; ++r) ob[r] = __float2bfloat16(o[f][r] * inv);
      *reinterpret_cast<uint2*>(
          &Y[((size_t)(b * 2048 + qrow)) * 2048 + h * 128 + f * 16 + lc * 4]) =
          *reinterpret_cast<uint2*>(ob);
    }
  }
}

// ---------------- launch ----------------
extern "C" void kernel_launch(void* const* d_in, const int* in_sizes, int n_in,
                              void* d_out, int out_size, void* d_ws, size_t ws_size,
                              hipStream_t stream) {
  const float* x = (const float*)d_in[0];
  const float* cosp = (const float*)d_in[1];
  const float* sinp = (const float*)d_in[2];
  const float* Wa = (const float*)d_in[3];
  const float* Wp = (const float*)d_in[4];
  float* out = (float*)d_out;

  bf16_t* ws = (bf16_t*)d_ws;
  bf16_t* xb = ws;                  // x bf16 -> reused as Q
  bf16_t* wab = ws + 8388608;       // W_attn bf16 -> reused as K (first 2.1M) + Vt
  bf16_t* wpb = ws + 14680064;      // W_proj bf16
  bf16_t* qkv = ws + 18874368;      // qkv bf16 -> reused as Y
  bf16_t* Q = xb;                   // [B][H][T][HS]
  bf16_t* Kr = wab;                 // [B][G][T][HS]  (wab[0 .. 2097152))
  bf16_t* Vt = wab + 2097152;       // [B][G][HS][T]  (dead wab space; NOT in qkv!)
  bf16_t* Y = qkv;                  // [B][T][H][HS]

  // fused converts: 2359296 groups of 8 = x(1048576) + Wa(786432) + Wp(524288)
  cvt3<<<9216, 256, 0, stream>>>(x, Wa, Wp, xb, wab, wpb);

  // qkv = xb @ wab^T : M=4096 N=3072 K=2048  (BN=192 -> 256 blocks)
  gemm256<192, bf16_t><<<dim3(16, 16), 512, 0, stream>>>(xb, wab, qkv, 4096, 3072, 2048);

  // fused RoPE(Q,K) + V transpose (one dispatch; Vt disjoint from qkv)
  rope_tv<<<4096, 320, 0, stream>>>(qkv, cosp, sinp, Q, Kr, Vt);

  attn_swa<<<dim3(24, 16, 2), 256, 0, stream>>>(Q, Kr, Vt, Y);

  // out = Y @ wpb^T : M=4096 N=2048 K=2048  (BN=128 -> 256 blocks)
  gemm256<128, float><<<dim3(16, 16), 512, 0, stream>>>(Y, wpb, out, 4096, 2048, 2048);
}

// Round 20
// 200.506 us; speedup vs baseline: 1.1242x; 1.0011x over previous
//
#include <hip/hip_runtime.h>
#include <hip/hip_bf16.h>
#include <cstdint>
#include <type_traits>

using bf16_t = __hip_bfloat16;
typedef __bf16 bf16x8 __attribute__((ext_vector_type(8)));
typedef float f32x4 __attribute__((ext_vector_type(4)));

typedef __attribute__((address_space(3))) uint32_t lds_u32_t;
typedef const __attribute__((address_space(1))) uint32_t glb_u32_t;

// ---------------- fused f32 -> bf16 convert (x, W_attn, W_proj) ----------
__global__ void cvt3(const float* __restrict__ x, const float* __restrict__ wa,
                     const float* __restrict__ wp, bf16_t* __restrict__ xb,
                     bf16_t* __restrict__ wab, bf16_t* __restrict__ wpb) {
  int i = blockIdx.x * blockDim.x + threadIdx.x;  // group of 8 elems
  const float* src;
  bf16_t* dst;
  int off;
  if (i < 1048576) {
    src = x; dst = xb; off = i;
  } else if (i < 1835008) {
    src = wa; dst = wab; off = i - 1048576;
  } else {
    src = wp; dst = wpb; off = i - 1835008;
  }
  const float4* p = reinterpret_cast<const float4*>(src) + (size_t)off * 2;
  float4 a = p[0];
  float4 b = p[1];
  bf16_t o[8];
  o[0] = __float2bfloat16(a.x); o[1] = __float2bfloat16(a.y);
  o[2] = __float2bfloat16(a.z); o[3] = __float2bfloat16(a.w);
  o[4] = __float2bfloat16(b.x); o[5] = __float2bfloat16(b.y);
  o[6] = __float2bfloat16(b.z); o[7] = __float2bfloat16(b.w);
  *reinterpret_cast<uint4*>(dst + (size_t)off * 8) = *reinterpret_cast<const uint4*>(o);
}

// ---------------- bf16 GEMM, 256xBN tile, counted-vmcnt pipeline ---------
// r13 schedule (confirmed local optimum) with 4Mx2N wave split: per-wave
// 64 x BN/2 output. LDS re-read per CU per K-tile drops 192->160 KB
// (A re-read 2x instead of 4x; B 4x instead of 2x; A panel is bigger).
// 512 thr = 8 waves, BK=64, LDS dbuf, grid = 256 blocks = 1/CU.
// 1-tile-lag counted waits; never vmcnt(0) in steady state. T2 swizzle via
// pre-swizzled source + swizzled ds_read. T1 bijective XCD swizzle.
template <int BN, typename OutT>
__global__ __launch_bounds__(512, 2) void gemm256(const bf16_t* __restrict__ A,
                                                  const bf16_t* __restrict__ Bt,
                                                  OutT* __restrict__ C,
                                                  int M, int N, int K) {
  constexpr int JN = BN / 32;        // B j-fragments per wave (4Mx2N split)
  constexpr int BL = BN / 64;        // B staging loads per thread
  __shared__ __align__(16) bf16_t As[2 * 256 * 64];
  __shared__ __align__(16) bf16_t Bs[2 * BN * 64];
  const int tid = threadIdx.x;
  const int lane = tid & 63;
  const int w = tid >> 6;
  const int wm = w >> 1, wn = w & 1;   // 4 M-waves x 2 N-waves
  const int lr = lane & 15, lc = lane >> 4;

  const int nwg = gridDim.x * gridDim.y;
  const int orig = blockIdx.y * gridDim.x + blockIdx.x;
  const int cpx = nwg >> 3;
  const int swz = (orig & 7) * cpx + (orig >> 3);
  const int bx = swz % gridDim.x, by = swz / gridDim.x;
  const int m0 = by * 256, n0 = bx * BN;

  const int srow = tid >> 3;
  const int scol = ((tid & 7) ^ (srow & 7)) * 8;
  const bf16_t* Asrc = A + (size_t)(m0 + srow) * K + scol;
  const bf16_t* Bsrc = Bt + (size_t)(n0 + srow) * K + scol;

  f32x4 acc[4][JN] = {};

  auto stageA = [&](int bufi, int kt) {
#pragma unroll
    for (int l = 0; l < 4; ++l)
      __builtin_amdgcn_global_load_lds(
          (glb_u32_t*)(Asrc + (size_t)kt * 64 + (size_t)l * 64 * K),
          (lds_u32_t*)(As + bufi * 16384 + l * 4096 + w * 512), 16, 0, 0);
  };
  auto stageB = [&](int bufi, int kt) {
#pragma unroll
    for (int l = 0; l < BL; ++l)
      __builtin_amdgcn_global_load_lds(
          (glb_u32_t*)(Bsrc + (size_t)kt * 64 + (size_t)l * 64 * K),
          (lds_u32_t*)(Bs + bufi * BN * 64 + l * 4096 + w * 512), 16, 0, 0);
  };

  const int nt = K >> 6;
  stageA(0, 0);
  stageB(0, 0);

  bf16x8 a[4][2], bb[JN][2];
  for (int t = 0; t < nt; ++t) {
    const int buf = t & 1;
    const char* Ab = (const char*)(As + buf * 16384);
    const char* Bb = (const char*)(Bs + buf * BN * 64);
    const bool st = (t + 1 < nt);

    auto rdA = [&](int i, int kk) {
      int R = wm * 64 + i * 16 + lr;
      return *reinterpret_cast<const bf16x8*>(
          Ab + R * 128 + ((kk * 64 + lc * 16) ^ ((R & 7) << 4)));
    };
    auto rdB = [&](int j, int kk) {
      int R = wn * (BN / 2) + j * 16 + lr;
      return *reinterpret_cast<const bf16x8*>(
          Bb + R * 128 + ((kk * 64 + lc * 16) ^ ((R & 7) << 4)));
    };

    // phase A: own A(t) landed (issued a full tile ago); B(t) in flight.
    if constexpr (BL == 3) {
      asm volatile("s_waitcnt vmcnt(3)" ::: "memory");
    } else {
      asm volatile("s_waitcnt vmcnt(2)" ::: "memory");
    }
    __builtin_amdgcn_s_barrier();
#pragma unroll
    for (int i = 0; i < 4; ++i) { a[i][0] = rdA(i, 0); a[i][1] = rdA(i, 1); }
    if (st) stageA(buf ^ 1, t + 1);

    // phase B: own B(t) landed; A(t+1) stays in flight (count 4).
    if (st) {
      asm volatile("s_waitcnt vmcnt(4)" ::: "memory");
    } else {
      asm volatile("s_waitcnt vmcnt(0)" ::: "memory");
    }
    __builtin_amdgcn_s_barrier();
#pragma unroll
    for (int j = 0; j < JN; ++j) { bb[j][0] = rdB(j, 0); bb[j][1] = rdB(j, 1); }
    if (st) stageB(buf ^ 1, t + 1);

    __builtin_amdgcn_s_setprio(1);
#pragma unroll
    for (int i = 0; i < 4; ++i)
#pragma unroll
      for (int j = 0; j < JN; ++j) {
        acc[i][j] = __builtin_amdgcn_mfma_f32_16x16x32_bf16(a[i][0], bb[j][0], acc[i][j], 0, 0, 0);
        acc[i][j] = __builtin_amdgcn_mfma_f32_16x16x32_bf16(a[i][1], bb[j][1], acc[i][j], 0, 0, 0);
      }
    __builtin_amdgcn_s_setprio(0);
  }

  // epilogue: C/D layout col=lane&15, row=(lane>>4)*4+reg  [m89/m91]
#pragma unroll
  for (int i = 0; i < 4; ++i)
#pragma unroll
    for (int j = 0; j < JN; ++j) {
      int row = m0 + wm * 64 + i * 16 + lc * 4;
      int col = n0 + wn * (BN / 2) + j * 16 + lr;
#pragma unroll
      for (int r = 0; r < 4; ++r) {
        float v = acc[i][j][r];
        if constexpr (std::is_same<OutT, float>::value)
          C[(size_t)(row + r) * N + col] = v;
        else
          C[(size_t)(row + r) * N + col] = __float2bfloat16(v);
      }
    }
}

// ---------------- fused RoPE(Q,K) + V-transpose, one dispatch ------------
// Blocks 0..2047: rope (2 rows x 160 pair-units, 320 threads, no idle).
// Blocks 2048..4095: V-slice transpose qkv -> Vt (first 256 threads).
// Vt lives in dead wab space (disjoint from qkv/Q/K/wpb) -- no race.
__global__ __launch_bounds__(320) void rope_tv(const bf16_t* __restrict__ qkv,
                                               const float* __restrict__ cosp,
                                               const float* __restrict__ sinp,
                                               bf16_t* __restrict__ Q,
                                               bf16_t* __restrict__ K,
                                               bf16_t* __restrict__ Vt) {
  if (blockIdx.x < 2048) {
    const int row = blockIdx.x * 2 + (threadIdx.x >= 160 ? 1 : 0);
    const int u = threadIdx.x >= 160 ? threadIdx.x - 160 : threadIdx.x;  // 0..159
    const int b = row >> 11, t = row & 2047;
    const int g = u / 40;
    const int r = u - g * 40;
    const int slot = r >> 3;     // 0..4
    const int d0 = (r & 7) * 8;  // 0..56 (lower half)

    const bf16_t* src = qkv + (size_t)row * 3072 + g * 768 + slot * 128 + d0;
    short lo[8], hi[8];
    *reinterpret_cast<uint4*>(lo) = *reinterpret_cast<const uint4*>(src);
    *reinterpret_cast<uint4*>(hi) = *reinterpret_cast<const uint4*>(src + 64);
    float4 c0 = *reinterpret_cast<const float4*>(cosp + t * 128 + d0);
    float4 c1 = *reinterpret_cast<const float4*>(cosp + t * 128 + d0 + 4);
    float4 s0 = *reinterpret_cast<const float4*>(sinp + t * 128 + d0);
    float4 s1 = *reinterpret_cast<const float4*>(sinp + t * 128 + d0 + 4);
    float cs[8] = {c0.x, c0.y, c0.z, c0.w, c1.x, c1.y, c1.z, c1.w};
    float sn[8] = {s0.x, s0.y, s0.z, s0.w, s1.x, s1.y, s1.z, s1.w};

    const bool isq = (slot < 4);
    // Q gets softmax scale 1/sqrt(128) * log2(e) folded (attn uses exp2)
    const float scale = isq ? (0.08838834764831843f * 1.4426950408889634f) : 1.0f;

    bf16_t olo[8], ohi[8];
#pragma unroll
    for (int e = 0; e < 8; ++e) {
      float x1 = __bfloat162float(*reinterpret_cast<const bf16_t*>(&lo[e]));
      float x2 = __bfloat162float(*reinterpret_cast<const bf16_t*>(&hi[e]));
      olo[e] = __float2bfloat16((x1 * cs[e] - x2 * sn[e]) * scale);
      ohi[e] = __float2bfloat16((x2 * cs[e] + x1 * sn[e]) * scale);
    }

    bf16_t* dst;
    if (isq) {
      int h = g * 4 + slot;
      dst = Q + (((size_t)(b * 16 + h)) * 2048 + t) * 128 + d0;
    } else {
      dst = K + (((size_t)(b * 4 + g)) * 2048 + t) * 128 + d0;
    }
    *reinterpret_cast<uint4*>(dst) = *reinterpret_cast<const uint4*>(olo);
    *reinterpret_cast<uint4*>(dst + 64) = *reinterpret_cast<const uint4*>(ohi);
  } else {
    __shared__ bf16_t tile[32][33];
    const int bid = blockIdx.x - 2048;
    const int t0 = (bid & 63) * 32;
    const int d0 = ((bid >> 6) & 3) * 32;
    const int bg = bid >> 8;
    const int b = bg >> 2, g = bg & 3;
    const bf16_t* src = qkv + (size_t)b * 2048 * 3072 + g * 768 + 640;
    bf16_t* dst = Vt + (size_t)bg * 128 * 2048;
    const int tx = threadIdx.x & 31, ty = threadIdx.x >> 5;  // ty 0..9
    if (ty < 8) {
#pragma unroll
      for (int i = ty; i < 32; i += 8)
        tile[i][tx] = src[(size_t)(t0 + i) * 3072 + d0 + tx];
    }
    __syncthreads();
    if (ty < 8) {
#pragma unroll
      for (int i = ty; i < 32; i += 8)
        dst[(size_t)(d0 + i) * 2048 + t0 + tx] = tile[tx][i];
    }
  }
}

// ---------------- sliding-window flash attention (v10, plateau) ----------
#define VROW 40
__global__ __launch_bounds__(256) void attn_swa(const bf16_t* __restrict__ Q,
                                                const bf16_t* __restrict__ K,
                                                const bf16_t* __restrict__ Vt,
                                                bf16_t* __restrict__ Y) {
  __shared__ __align__(16) bf16_t Ks[2 * 32 * 128];
  __shared__ __align__(16) bf16_t Vs[2 * 128 * VROW];

  const int tid = threadIdx.x;
  const int lane = tid & 63;
  const int w = tid >> 6;
  const int lr = lane & 15, lc = lane >> 4;
  const int b = blockIdx.z, h = blockIdx.y;
  const int g = h >> 2;

  int nseg, sx0, sx1 = 0;
  if (blockIdx.x < 16) {
    nseg = 1;
    sx0 = blockIdx.x + 16;
  } else {
    nseg = 2;
    sx0 = blockIdx.x - 16;
    sx1 = 15 - sx0;
  }

  const bf16_t* Qp = Q + ((size_t)(b * 16 + h) * 2048) * 128;
  const bf16_t* Kp = K + ((size_t)(b * 4 + g) * 2048) * 128;
  const bf16_t* Vp = Vt + ((size_t)(b * 4 + g) * 128) * 2048;

  const int kmj = tid >> 4;
  const int kmc = ((tid & 15) ^ (kmj & 7)) * 8;
  const bf16_t* Ksrc = Kp + (size_t)kmj * 128 + kmc;
  const int vd = tid >> 2, vc = tid & 3;
  const bf16_t* Vsrc = Vp + (size_t)vd * 2048 + vc * 8;
  const int vdst = vd * VROW + (vc & 1) * 16 + (vc >> 1) * 4;

  auto loadK = [&](int j0, uint4& ka, uint4& kb) {
    const bf16_t* s = Ksrc + (size_t)j0 * 128;
    ka = *reinterpret_cast<const uint4*>(s);
    kb = *reinterpret_cast<const uint4*>(s + 16 * 128);
  };
  auto writeK = [&](int bufi, uint4 ka, uint4 kb) {
    *reinterpret_cast<uint4*>(Ks + bufi * 4096 + tid * 8) = ka;
    *reinterpret_cast<uint4*>(Ks + bufi * 4096 + 2048 + tid * 8) = kb;
  };
  auto loadV = [&](int j0, uint4& a, uint4& bqv) {
    a = *reinterpret_cast<const uint4*>(Vsrc + j0);
    bqv = *reinterpret_cast<const uint4*>(Vsrc + 64 * 2048 + j0);
  };
  auto writeV = [&](int bufi, uint4 a, uint4 bqv) {
    bf16_t* p = Vs + bufi * 128 * VROW + vdst;
    *reinterpret_cast<uint2*>(p) = make_uint2(a.x, a.y);
    *reinterpret_cast<uint2*>(p + 8) = make_uint2(a.z, a.w);
    bf16_t* p1 = p + 64 * VROW;
    *reinterpret_cast<uint2*>(p1) = make_uint2(bqv.x, bqv.y);
    *reinterpret_cast<uint2*>(p1 + 8) = make_uint2(bqv.z, bqv.w);
  };

  const int kxor = (lr & 7) << 4;

  for (int sidx = 0; sidx < nseg; ++sidx) {
    const int i0b = ((sidx == 0) ? sx0 : sx1) * 64;
    const int i0 = i0b + w * 16;
    const int qrow = i0 + lr;

    bf16x8 qf[4];
#pragma unroll
    for (int kc = 0; kc < 4; ++kc)
      qf[kc] = *reinterpret_cast<const bf16x8*>(&Qp[(size_t)qrow * 128 + kc * 32 + lc * 8]);

    f32x4 o[8] = {};
    float mrun = -1e30f, lrun = 0.f;  // lrun LANE-PARTIAL (reduced at epilogue)

    int lo = i0b - 1023;
    if (lo < 0) lo = 0;
    const int jstart = lo & ~31;
    const int jlast = i0b + 32;

    {
      uint4 ka, kb, va, vb;
      loadK(jstart, ka, kb);
      loadV(jstart, va, vb);
      writeK(0, ka, kb);
      writeV(0, va, vb);
    }
    __syncthreads();

    int buf = 0;
    for (int j0 = jstart; j0 <= jlast; j0 += 32) {
      const int nxt = j0 + 32;
      uint4 ka, kb, va, vb;
      const bool do_stage = (nxt <= jlast);
      if (do_stage) {
        loadK(nxt, ka, kb);
        loadV(nxt, va, vb);
      }

      const bool active = (j0 <= i0 + 15) && (j0 + 31 > i0 - 1024);
      if (active) {
        const bf16_t* Kb = Ks + buf * 4096;
        const bf16_t* Vb = Vs + buf * 128 * VROW;
        f32x4 s0 = {}, s1 = {};
        __builtin_amdgcn_s_setprio(1);
#pragma unroll
        for (int kc = 0; kc < 4; ++kc) {
          int col = ((kc * 64 + lc * 16) ^ kxor) >> 1;
          bf16x8 kf0 = *reinterpret_cast<const bf16x8*>(Kb + lr * 128 + col);
          bf16x8 kf1 = *reinterpret_cast<const bf16x8*>(Kb + (16 + lr) * 128 + col);
          s0 = __builtin_amdgcn_mfma_f32_16x16x32_bf16(kf0, qf[kc], s0, 0, 0, 0);
          s1 = __builtin_amdgcn_mfma_f32_16x16x32_bf16(kf1, qf[kc], s1, 0, 0, 0);
        }
        __builtin_amdgcn_s_setprio(0);
        bf16x8 vvf[8];
#pragma unroll
        for (int f = 0; f < 8; ++f)
          vvf[f] = *reinterpret_cast<const bf16x8*>(Vb + (f * 16 + lr) * VROW + lc * 8);

        const bool full = (j0 + 31 <= i0) && (j0 >= i0 - 1008);
        if (!full) {
#pragma unroll
          for (int r = 0; r < 4; ++r) {
            int ja = j0 + lc * 4 + r;
            int jb = ja + 16;
            bool oka = (ja <= qrow) && (ja > qrow - 1024);
            bool okb = (jb <= qrow) && (jb > qrow - 1024);
            s0[r] = oka ? s0[r] : -1e30f;
            s1[r] = okb ? s1[r] : -1e30f;
          }
        }
        float rm = fmaxf(fmaxf(fmaxf(s0[0], s0[1]), fmaxf(s0[2], s0[3])),
                         fmaxf(fmaxf(s1[0], s1[1]), fmaxf(s1[2], s1[3])));

        if (!__all(rm <= mrun + 11.5f)) {
          rm = fmaxf(rm, __shfl_xor(rm, 16));
          rm = fmaxf(rm, __shfl_xor(rm, 32));
          float mnew = fmaxf(mrun, rm);
          float alpha = exp2f(mrun - mnew);
          mrun = mnew;
          lrun *= alpha;
#pragma unroll
          for (int f = 0; f < 8; ++f)
#pragma unroll
            for (int r = 0; r < 4; ++r) o[f][r] *= alpha;
        }

        float p0[4], p1[4], ps = 0.f;
#pragma unroll
        for (int r = 0; r < 4; ++r) {
          p0[r] = exp2f(s0[r] - mrun);
          p1[r] = exp2f(s1[r] - mrun);
          ps += p0[r] + p1[r];
        }
        lrun += ps;

        bf16_t pb[8];
#pragma unroll
        for (int r = 0; r < 4; ++r) {
          pb[r] = __float2bfloat16(p0[r]);
          pb[r + 4] = __float2bfloat16(p1[r]);
        }
        bf16x8 pfrag = *reinterpret_cast<bf16x8*>(pb);

        __builtin_amdgcn_s_setprio(1);
#pragma unroll
        for (int f = 0; f < 8; ++f)
          o[f] = __builtin_amdgcn_mfma_f32_16x16x32_bf16(vvf[f], pfrag, o[f], 0, 0, 0);
        __builtin_amdgcn_s_setprio(0);
      }

      if (do_stage) {
        writeK(buf ^ 1, ka, kb);
        writeV(buf ^ 1, va, vb);
      }
      __syncthreads();
      buf ^= 1;
    }

    float lt = lrun;
    lt += __shfl_xor(lt, 16);
    lt += __shfl_xor(lt, 32);
    float inv = 1.f / lt;
#pragma unroll
    for (int f = 0; f < 8; ++f) {
      bf16_t ob[4];
#pragma unroll
      for (int r = 0; r < 4; ++r) ob[r] = __float2bfloat16(o[f][r] * inv);
      *reinterpret_cast<uint2*>(
          &Y[((size_t)(b * 2048 + qrow)) * 2048 + h * 128 + f * 16 + lc * 4]) =
          *reinterpret_cast<uint2*>(ob);
    }
  }
}

// ---------------- launch ----------------
extern "C" void kernel_launch(void* const* d_in, const int* in_sizes, int n_in,
                              void* d_out, int out_size, void* d_ws, size_t ws_size,
                              hipStream_t stream) {
  const float* x = (const float*)d_in[0];
  const float* cosp = (const float*)d_in[1];
  const float* sinp = (const float*)d_in[2];
  const float* Wa = (const float*)d_in[3];
  const float* Wp = (const float*)d_in[4];
  float* out = (float*)d_out;

  bf16_t* ws = (bf16_t*)d_ws;
  bf16_t* xb = ws;                  // x bf16 -> reused as Q
  bf16_t* wab = ws + 8388608;       // W_attn bf16 -> reused as K (first 2.1M) + Vt
  bf16_t* wpb = ws + 14680064;      // W_proj bf16
  bf16_t* qkv = ws + 18874368;      // qkv bf16 -> reused as Y
  bf16_t* Q = xb;                   // [B][H][T][HS]
  bf16_t* Kr = wab;                 // [B][G][T][HS]  (wab[0 .. 2097152))
  bf16_t* Vt = wab + 2097152;       // [B][G][HS][T]  (dead wab space)
  bf16_t* Y = qkv;                  // [B][T][H][HS]

  // fused converts: 2359296 groups of 8 = x(1048576) + Wa(786432) + Wp(524288)
  cvt3<<<9216, 256, 0, stream>>>(x, Wa, Wp, xb, wab, wpb);

  // qkv = xb @ wab^T : M=4096 N=3072 K=2048  (BN=192 -> 256 blocks)
  gemm256<192, bf16_t><<<dim3(16, 16), 512, 0, stream>>>(xb, wab, qkv, 4096, 3072, 2048);

  // fused RoPE(Q,K) + V transpose (one dispatch; Vt disjoint from qkv)
  rope_tv<<<4096, 320, 0, stream>>>(qkv, cosp, sinp, Q, Kr, Vt);

  attn_swa<<<dim3(24, 16, 2), 256, 0, stream>>>(Q, Kr, Vt, Y);

  // out = Y @ wpb^T : M=4096 N=2048 K=2048  (BN=128 -> 256 blocks)
  gemm256<128, float><<<dim3(16, 16), 512, 0, stream>>>(Y, wpb, out, 4096, 2048, 2048);
}

// Round 21
// 199.452 us; speedup vs baseline: 1.1302x; 1.0053x over previous
//
#include <hip/hip_runtime.h>
#include <hip/hip_bf16.h>
#include <cstdint>
#include <type_traits>

using bf16_t = __hip_bfloat16;
typedef __bf16 bf16x8 __attribute__((ext_vector_type(8)));
typedef float f32x4 __attribute__((ext_vector_type(4)));

typedef __attribute__((address_space(3))) uint32_t lds_u32_t;
typedef const __attribute__((address_space(1))) uint32_t glb_u32_t;

// ---------------- fused f32 -> bf16 convert (x, W_attn, W_proj) ----------
__global__ void cvt3(const float* __restrict__ x, const float* __restrict__ wa,
                     const float* __restrict__ wp, bf16_t* __restrict__ xb,
                     bf16_t* __restrict__ wab, bf16_t* __restrict__ wpb) {
  int i = blockIdx.x * blockDim.x + threadIdx.x;  // group of 8 elems
  const float* src;
  bf16_t* dst;
  int off;
  if (i < 1048576) {
    src = x; dst = xb; off = i;
  } else if (i < 1835008) {
    src = wa; dst = wab; off = i - 1048576;
  } else {
    src = wp; dst = wpb; off = i - 1835008;
  }
  const float4* p = reinterpret_cast<const float4*>(src) + (size_t)off * 2;
  float4 a = p[0];
  float4 b = p[1];
  bf16_t o[8];
  o[0] = __float2bfloat16(a.x); o[1] = __float2bfloat16(a.y);
  o[2] = __float2bfloat16(a.z); o[3] = __float2bfloat16(a.w);
  o[4] = __float2bfloat16(b.x); o[5] = __float2bfloat16(b.y);
  o[6] = __float2bfloat16(b.z); o[7] = __float2bfloat16(b.w);
  *reinterpret_cast<uint4*>(dst + (size_t)off * 8) = *reinterpret_cast<const uint4*>(o);
}

// ---------------- bf16 GEMM, 256xBN tile, counted-vmcnt pipeline ---------
// r13 schedule (confirmed local optimum) with 4Mx2N wave split: per-wave
// 64 x BN/2 output. LDS re-read per CU per K-tile drops 192->160 KB
// (A re-read 2x instead of 4x; B 4x instead of 2x; A panel is bigger).
// 512 thr = 8 waves, BK=64, LDS dbuf, grid = 256 blocks = 1/CU.
// 1-tile-lag counted waits; never vmcnt(0) in steady state. T2 swizzle via
// pre-swizzled source + swizzled ds_read. T1 bijective XCD swizzle.
template <int BN, typename OutT>
__global__ __launch_bounds__(512, 2) void gemm256(const bf16_t* __restrict__ A,
                                                  const bf16_t* __restrict__ Bt,
                                                  OutT* __restrict__ C,
                                                  int M, int N, int K) {
  constexpr int JN = BN / 32;        // B j-fragments per wave (4Mx2N split)
  constexpr int BL = BN / 64;        // B staging loads per thread
  __shared__ __align__(16) bf16_t As[2 * 256 * 64];
  __shared__ __align__(16) bf16_t Bs[2 * BN * 64];
  const int tid = threadIdx.x;
  const int lane = tid & 63;
  const int w = tid >> 6;
  const int wm = w >> 1, wn = w & 1;   // 4 M-waves x 2 N-waves
  const int lr = lane & 15, lc = lane >> 4;

  const int nwg = gridDim.x * gridDim.y;
  const int orig = blockIdx.y * gridDim.x + blockIdx.x;
  const int cpx = nwg >> 3;
  const int swz = (orig & 7) * cpx + (orig >> 3);
  const int bx = swz % gridDim.x, by = swz / gridDim.x;
  const int m0 = by * 256, n0 = bx * BN;

  const int srow = tid >> 3;
  const int scol = ((tid & 7) ^ (srow & 7)) * 8;
  const bf16_t* Asrc = A + (size_t)(m0 + srow) * K + scol;
  const bf16_t* Bsrc = Bt + (size_t)(n0 + srow) * K + scol;

  f32x4 acc[4][JN] = {};

  auto stageA = [&](int bufi, int kt) {
#pragma unroll
    for (int l = 0; l < 4; ++l)
      __builtin_amdgcn_global_load_lds(
          (glb_u32_t*)(Asrc + (size_t)kt * 64 + (size_t)l * 64 * K),
          (lds_u32_t*)(As + bufi * 16384 + l * 4096 + w * 512), 16, 0, 0);
  };
  auto stageB = [&](int bufi, int kt) {
#pragma unroll
    for (int l = 0; l < BL; ++l)
      __builtin_amdgcn_global_load_lds(
          (glb_u32_t*)(Bsrc + (size_t)kt * 64 + (size_t)l * 64 * K),
          (lds_u32_t*)(Bs + bufi * BN * 64 + l * 4096 + w * 512), 16, 0, 0);
  };

  const int nt = K >> 6;
  stageA(0, 0);
  stageB(0, 0);

  bf16x8 a[4][2], bb[JN][2];
  for (int t = 0; t < nt; ++t) {
    const int buf = t & 1;
    const char* Ab = (const char*)(As + buf * 16384);
    const char* Bb = (const char*)(Bs + buf * BN * 64);
    const bool st = (t + 1 < nt);

    auto rdA = [&](int i, int kk) {
      int R = wm * 64 + i * 16 + lr;
      return *reinterpret_cast<const bf16x8*>(
          Ab + R * 128 + ((kk * 64 + lc * 16) ^ ((R & 7) << 4)));
    };
    auto rdB = [&](int j, int kk) {
      int R = wn * (BN / 2) + j * 16 + lr;
      return *reinterpret_cast<const bf16x8*>(
          Bb + R * 128 + ((kk * 64 + lc * 16) ^ ((R & 7) << 4)));
    };

    // phase A: own A(t) landed (issued a full tile ago); B(t) in flight.
    if constexpr (BL == 3) {
      asm volatile("s_waitcnt vmcnt(3)" ::: "memory");
    } else {
      asm volatile("s_waitcnt vmcnt(2)" ::: "memory");
    }
    __builtin_amdgcn_s_barrier();
#pragma unroll
    for (int i = 0; i < 4; ++i) { a[i][0] = rdA(i, 0); a[i][1] = rdA(i, 1); }
    if (st) stageA(buf ^ 1, t + 1);

    // phase B: own B(t) landed; A(t+1) stays in flight (count 4).
    if (st) {
      asm volatile("s_waitcnt vmcnt(4)" ::: "memory");
    } else {
      asm volatile("s_waitcnt vmcnt(0)" ::: "memory");
    }
    __builtin_amdgcn_s_barrier();
#pragma unroll
    for (int j = 0; j < JN; ++j) { bb[j][0] = rdB(j, 0); bb[j][1] = rdB(j, 1); }
    if (st) stageB(buf ^ 1, t + 1);

    __builtin_amdgcn_s_setprio(1);
#pragma unroll
    for (int i = 0; i < 4; ++i)
#pragma unroll
      for (int j = 0; j < JN; ++j) {
        acc[i][j] = __builtin_amdgcn_mfma_f32_16x16x32_bf16(a[i][0], bb[j][0], acc[i][j], 0, 0, 0);
        acc[i][j] = __builtin_amdgcn_mfma_f32_16x16x32_bf16(a[i][1], bb[j][1], acc[i][j], 0, 0, 0);
      }
    __builtin_amdgcn_s_setprio(0);
  }

  // epilogue: C/D layout col=lane&15, row=(lane>>4)*4+reg  [m89/m91]
#pragma unroll
  for (int i = 0; i < 4; ++i)
#pragma unroll
    for (int j = 0; j < JN; ++j) {
      int row = m0 + wm * 64 + i * 16 + lc * 4;
      int col = n0 + wn * (BN / 2) + j * 16 + lr;
#pragma unroll
      for (int r = 0; r < 4; ++r) {
        float v = acc[i][j][r];
        if constexpr (std::is_same<OutT, float>::value)
          C[(size_t)(row + r) * N + col] = v;
        else
          C[(size_t)(row + r) * N + col] = __float2bfloat16(v);
      }
    }
}

// ---------------- fused RoPE(Q,K) + V-transpose, one dispatch ------------
// Blocks 0..2047: rope (2 rows x 160 pair-units, 320 threads, no idle).
// Blocks 2048..4095: V-slice transpose qkv -> Vt (first 256 threads).
// Vt lives in dead wab space (disjoint from qkv/Q/K/wpb) -- no race.
__global__ __launch_bounds__(320) void rope_tv(const bf16_t* __restrict__ qkv,
                                               const float* __restrict__ cosp,
                                               const float* __restrict__ sinp,
                                               bf16_t* __restrict__ Q,
                                               bf16_t* __restrict__ K,
                                               bf16_t* __restrict__ Vt) {
  if (blockIdx.x < 2048) {
    const int row = blockIdx.x * 2 + (threadIdx.x >= 160 ? 1 : 0);
    const int u = threadIdx.x >= 160 ? threadIdx.x - 160 : threadIdx.x;  // 0..159
    const int b = row >> 11, t = row & 2047;
    const int g = u / 40;
    const int r = u - g * 40;
    const int slot = r >> 3;     // 0..4
    const int d0 = (r & 7) * 8;  // 0..56 (lower half)

    const bf16_t* src = qkv + (size_t)row * 3072 + g * 768 + slot * 128 + d0;
    short lo[8], hi[8];
    *reinterpret_cast<uint4*>(lo) = *reinterpret_cast<const uint4*>(src);
    *reinterpret_cast<uint4*>(hi) = *reinterpret_cast<const uint4*>(src + 64);
    float4 c0 = *reinterpret_cast<const float4*>(cosp + t * 128 + d0);
    float4 c1 = *reinterpret_cast<const float4*>(cosp + t * 128 + d0 + 4);
    float4 s0 = *reinterpret_cast<const float4*>(sinp + t * 128 + d0);
    float4 s1 = *reinterpret_cast<const float4*>(sinp + t * 128 + d0 + 4);
    float cs[8] = {c0.x, c0.y, c0.z, c0.w, c1.x, c1.y, c1.z, c1.w};
    float sn[8] = {s0.x, s0.y, s0.z, s0.w, s1.x, s1.y, s1.z, s1.w};

    const bool isq = (slot < 4);
    // Q gets softmax scale 1/sqrt(128) * log2(e) folded (attn uses exp2)
    const float scale = isq ? (0.08838834764831843f * 1.4426950408889634f) : 1.0f;

    bf16_t olo[8], ohi[8];
#pragma unroll
    for (int e = 0; e < 8; ++e) {
      float x1 = __bfloat162float(*reinterpret_cast<const bf16_t*>(&lo[e]));
      float x2 = __bfloat162float(*reinterpret_cast<const bf16_t*>(&hi[e]));
      olo[e] = __float2bfloat16((x1 * cs[e] - x2 * sn[e]) * scale);
      ohi[e] = __float2bfloat16((x2 * cs[e] + x1 * sn[e]) * scale);
    }

    bf16_t* dst;
    if (isq) {
      int h = g * 4 + slot;
      dst = Q + (((size_t)(b * 16 + h)) * 2048 + t) * 128 + d0;
    } else {
      dst = K + (((size_t)(b * 4 + g)) * 2048 + t) * 128 + d0;
    }
    *reinterpret_cast<uint4*>(dst) = *reinterpret_cast<const uint4*>(olo);
    *reinterpret_cast<uint4*>(dst + 64) = *reinterpret_cast<const uint4*>(ohi);
  } else {
    __shared__ bf16_t tile[32][33];
    const int bid = blockIdx.x - 2048;
    const int t0 = (bid & 63) * 32;
    const int d0 = ((bid >> 6) & 3) * 32;
    const int bg = bid >> 8;
    const int b = bg >> 2, g = bg & 3;
    const bf16_t* src = qkv + (size_t)b * 2048 * 3072 + g * 768 + 640;
    bf16_t* dst = Vt + (size_t)bg * 128 * 2048;
    const int tx = threadIdx.x & 31, ty = threadIdx.x >> 5;  // ty 0..9
    if (ty < 8) {
#pragma unroll
      for (int i = ty; i < 32; i += 8)
        tile[i][tx] = src[(size_t)(t0 + i) * 3072 + d0 + tx];
    }
    __syncthreads();
    if (ty < 8) {
#pragma unroll
      for (int i = ty; i < 32; i += 8)
        dst[(size_t)(d0 + i) * 2048 + t0 + tx] = tile[tx][i];
    }
  }
}

// ---------------- sliding-window flash attention (v10, plateau) ----------
#define VROW 40
__global__ __launch_bounds__(256) void attn_swa(const bf16_t* __restrict__ Q,
                                                const bf16_t* __restrict__ K,
                                                const bf16_t* __restrict__ Vt,
                                                bf16_t* __restrict__ Y) {
  __shared__ __align__(16) bf16_t Ks[2 * 32 * 128];
  __shared__ __align__(16) bf16_t Vs[2 * 128 * VROW];

  const int tid = threadIdx.x;
  const int lane = tid & 63;
  const int w = tid >> 6;
  const int lr = lane & 15, lc = lane >> 4;
  const int b = blockIdx.z, h = blockIdx.y;
  const int g = h >> 2;

  int nseg, sx0, sx1 = 0;
  if (blockIdx.x < 16) {
    nseg = 1;
    sx0 = blockIdx.x + 16;
  } else {
    nseg = 2;
    sx0 = blockIdx.x - 16;
    sx1 = 15 - sx0;
  }

  const bf16_t* Qp = Q + ((size_t)(b * 16 + h) * 2048) * 128;
  const bf16_t* Kp = K + ((size_t)(b * 4 + g) * 2048) * 128;
  const bf16_t* Vp = Vt + ((size_t)(b * 4 + g) * 128) * 2048;

  const int kmj = tid >> 4;
  const int kmc = ((tid & 15) ^ (kmj & 7)) * 8;
  const bf16_t* Ksrc = Kp + (size_t)kmj * 128 + kmc;
  const int vd = tid >> 2, vc = tid & 3;
  const bf16_t* Vsrc = Vp + (size_t)vd * 2048 + vc * 8;
  const int vdst = vd * VROW + (vc & 1) * 16 + (vc >> 1) * 4;

  auto loadK = [&](int j0, uint4& ka, uint4& kb) {
    const bf16_t* s = Ksrc + (size_t)j0 * 128;
    ka = *reinterpret_cast<const uint4*>(s);
    kb = *reinterpret_cast<const uint4*>(s + 16 * 128);
  };
  auto writeK = [&](int bufi, uint4 ka, uint4 kb) {
    *reinterpret_cast<uint4*>(Ks + bufi * 4096 + tid * 8) = ka;
    *reinterpret_cast<uint4*>(Ks + bufi * 4096 + 2048 + tid * 8) = kb;
  };
  auto loadV = [&](int j0, uint4& a, uint4& bqv) {
    a = *reinterpret_cast<const uint4*>(Vsrc + j0);
    bqv = *reinterpret_cast<const uint4*>(Vsrc + 64 * 2048 + j0);
  };
  auto writeV = [&](int bufi, uint4 a, uint4 bqv) {
    bf16_t* p = Vs + bufi * 128 * VROW + vdst;
    *reinterpret_cast<uint2*>(p) = make_uint2(a.x, a.y);
    *reinterpret_cast<uint2*>(p + 8) = make_uint2(a.z, a.w);
    bf16_t* p1 = p + 64 * VROW;
    *reinterpret_cast<uint2*>(p1) = make_uint2(bqv.x, bqv.y);
    *reinterpret_cast<uint2*>(p1 + 8) = make_uint2(bqv.z, bqv.w);
  };

  const int kxor = (lr & 7) << 4;

  for (int sidx = 0; sidx < nseg; ++sidx) {
    const int i0b = ((sidx == 0) ? sx0 : sx1) * 64;
    const int i0 = i0b + w * 16;
    const int qrow = i0 + lr;

    bf16x8 qf[4];
#pragma unroll
    for (int kc = 0; kc < 4; ++kc)
      qf[kc] = *reinterpret_cast<const bf16x8*>(&Qp[(size_t)qrow * 128 + kc * 32 + lc * 8]);

    f32x4 o[8] = {};
    float mrun = -1e30f, lrun = 0.f;  // lrun LANE-PARTIAL (reduced at epilogue)

    int lo = i0b - 1023;
    if (lo < 0) lo = 0;
    const int jstart = lo & ~31;
    const int jlast = i0b + 32;

    {
      uint4 ka, kb, va, vb;
      loadK(jstart, ka, kb);
      loadV(jstart, va, vb);
      writeK(0, ka, kb);
      writeV(0, va, vb);
    }
    __syncthreads();

    int buf = 0;
    for (int j0 = jstart; j0 <= jlast; j0 += 32) {
      const int nxt = j0 + 32;
      uint4 ka, kb, va, vb;
      const bool do_stage = (nxt <= jlast);
      if (do_stage) {
        loadK(nxt, ka, kb);
        loadV(nxt, va, vb);
      }

      const bool active = (j0 <= i0 + 15) && (j0 + 31 > i0 - 1024);
      if (active) {
        const bf16_t* Kb = Ks + buf * 4096;
        const bf16_t* Vb = Vs + buf * 128 * VROW;
        f32x4 s0 = {}, s1 = {};
        __builtin_amdgcn_s_setprio(1);
#pragma unroll
        for (int kc = 0; kc < 4; ++kc) {
          int col = ((kc * 64 + lc * 16) ^ kxor) >> 1;
          bf16x8 kf0 = *reinterpret_cast<const bf16x8*>(Kb + lr * 128 + col);
          bf16x8 kf1 = *reinterpret_cast<const bf16x8*>(Kb + (16 + lr) * 128 + col);
          s0 = __builtin_amdgcn_mfma_f32_16x16x32_bf16(kf0, qf[kc], s0, 0, 0, 0);
          s1 = __builtin_amdgcn_mfma_f32_16x16x32_bf16(kf1, qf[kc], s1, 0, 0, 0);
        }
        __builtin_amdgcn_s_setprio(0);
        bf16x8 vvf[8];
#pragma unroll
        for (int f = 0; f < 8; ++f)
          vvf[f] = *reinterpret_cast<const bf16x8*>(Vb + (f * 16 + lr) * VROW + lc * 8);

        const bool full = (j0 + 31 <= i0) && (j0 >= i0 - 1008);
        if (!full) {
#pragma unroll
          for (int r = 0; r < 4; ++r) {
            int ja = j0 + lc * 4 + r;
            int jb = ja + 16;
            bool oka = (ja <= qrow) && (ja > qrow - 1024);
            bool okb = (jb <= qrow) && (jb > qrow - 1024);
            s0[r] = oka ? s0[r] : -1e30f;
            s1[r] = okb ? s1[r] : -1e30f;
          }
        }
        float rm = fmaxf(fmaxf(fmaxf(s0[0], s0[1]), fmaxf(s0[2], s0[3])),
                         fmaxf(fmaxf(s1[0], s1[1]), fmaxf(s1[2], s1[3])));

        if (!__all(rm <= mrun + 11.5f)) {
          rm = fmaxf(rm, __shfl_xor(rm, 16));
          rm = fmaxf(rm, __shfl_xor(rm, 32));
          float mnew = fmaxf(mrun, rm);
          float alpha = exp2f(mrun - mnew);
          mrun = mnew;
          lrun *= alpha;
#pragma unroll
          for (int f = 0; f < 8; ++f)
#pragma unroll
            for (int r = 0; r < 4; ++r) o[f][r] *= alpha;
        }

        float p0[4], p1[4], ps = 0.f;
#pragma unroll
        for (int r = 0; r < 4; ++r) {
          p0[r] = exp2f(s0[r] - mrun);
          p1[r] = exp2f(s1[r] - mrun);
          ps += p0[r] + p1[r];
        }
        lrun += ps;

        bf16_t pb[8];
#pragma unroll
        for (int r = 0; r < 4; ++r) {
          pb[r] = __float2bfloat16(p0[r]);
          pb[r + 4] = __float2bfloat16(p1[r]);
        }
        bf16x8 pfrag = *reinterpret_cast<bf16x8*>(pb);

        __builtin_amdgcn_s_setprio(1);
#pragma unroll
        for (int f = 0; f < 8; ++f)
          o[f] = __builtin_amdgcn_mfma_f32_16x16x32_bf16(vvf[f], pfrag, o[f], 0, 0, 0);
        __builtin_amdgcn_s_setprio(0);
      }

      if (do_stage) {
        writeK(buf ^ 1, ka, kb);
        writeV(buf ^ 1, va, vb);
      }
      __syncthreads();
      buf ^= 1;
    }

    float lt = lrun;
    lt += __shfl_xor(lt, 16);
    lt += __shfl_xor(lt, 32);
    float inv = 1.f / lt;
#pragma unroll
    for (int f = 0; f < 8; ++f) {
      bf16_t ob[4];
#pragma unroll
      for (int r = 0; r < 4; ++r) ob[r] = __float2bfloat16(o[f][r] * inv);
      *reinterpret_cast<uint2*>(
          &Y[((size_t)(b * 2048 + qrow)) * 2048 + h * 128 + f * 16 + lc * 4]) =
          *reinterpret_cast<uint2*>(ob);
    }
  }
}

// ---------------- launch ----------------
extern "C" void kernel_launch(void* const* d_in, const int* in_sizes, int n_in,
                              void* d_out, int out_size, void* d_ws, size_t ws_size,
                              hipStream_t stream) {
  const float* x = (const float*)d_in[0];
  const float* cosp = (const float*)d_in[1];
  const float* sinp = (const float*)d_in[2];
  const float* Wa = (const float*)d_in[3];
  const float* Wp = (const float*)d_in[4];
  float* out = (float*)d_out;

  bf16_t* ws = (bf16_t*)d_ws;
  bf16_t* xb = ws;                  // x bf16 -> reused as Q
  bf16_t* wab = ws + 8388608;       // W_attn bf16 -> reused as K (first 2.1M) + Vt
  bf16_t* wpb = ws + 14680064;      // W_proj bf16
  bf16_t* qkv = ws + 18874368;      // qkv bf16 -> reused as Y
  bf16_t* Q = xb;                   // [B][H][T][HS]
  bf16_t* Kr = wab;                 // [B][G][T][HS]  (wab[0 .. 2097152))
  bf16_t* Vt = wab + 2097152;       // [B][G][HS][T]  (dead wab space)
  bf16_t* Y = qkv;                  // [B][T][H][HS]

  // fused converts: 2359296 groups of 8 = x(1048576) + Wa(786432) + Wp(524288)
  cvt3<<<9216, 256, 0, stream>>>(x, Wa, Wp, xb, wab, wpb);

  // qkv = xb @ wab^T : M=4096 N=3072 K=2048  (BN=192 -> 256 blocks)
  gemm256<192, bf16_t><<<dim3(16, 16), 512, 0, stream>>>(xb, wab, qkv, 4096, 3072, 2048);

  // fused RoPE(Q,K) + V transpose (one dispatch; Vt disjoint from qkv)
  rope_tv<<<4096, 320, 0, stream>>>(qkv, cosp, sinp, Q, Kr, Vt);

  attn_swa<<<dim3(24, 16, 2), 256, 0, stream>>>(Q, Kr, Vt, Y);

  // out = Y @ wpb^T : M=4096 N=2048 K=2048  (BN=128 -> 256 blocks)
  gemm256<128, float><<<dim3(16, 16), 512, 0, stream>>>(Y, wpb, out, 4096, 2048, 2048);
}